// Round 9
// baseline (408.471 us; speedup 1.0000x reference)
//
#include <hip/hip_runtime.h>
#include <hip/hip_bf16.h>
#include <math.h>

typedef __hip_bfloat16 bf16;
typedef unsigned int u32;
typedef __attribute__((ext_vector_type(8))) short bf16x8;
typedef __attribute__((ext_vector_type(4))) float f32x4;

#define BATCH 2
#define SEQ 1024
#define DM 1024
#define DI 2048
#define NST 16
#define DTR 64
#define XDN 96          // dt_rank + 2*N = 64+32
#define XDP_LD 128      // padded x_dbl row
#define T_TOK 2048      // BATCH*SEQ
#define N2 4096         // 2*DI

static __device__ __forceinline__ float b2f(bf16 v) { return __bfloat162float(v); }
static __device__ __forceinline__ float bits2f(unsigned short u) {
    return __uint_as_float(((unsigned)u) << 16);
}

// fast softplus: 2 HW transcendentals instead of libm log1pf (branchy, ~5x VALU)
static __device__ __forceinline__ float softplus_fast(float t) {
    return (t > 20.f) ? t : __logf(1.f + __expf(t));
}

// ---- async global->LDS, 16 bytes per lane; LDS dest must be wave-uniform base ----
static __device__ __forceinline__ void gload_lds16(const void* g, void* l) {
    __builtin_amdgcn_global_load_lds((__attribute__((address_space(1))) u32*)(size_t)g,
                                     (__attribute__((address_space(3))) u32*)l, 16, 0, 0);
}

// compiler memory fence + raw barrier (no vmcnt drain, unlike __syncthreads)
#define SBAR() do { asm volatile("" ::: "memory"); __builtin_amdgcn_s_barrier(); asm volatile("" ::: "memory"); } while (0)

// ---- 32x32 LDS tile transpose helper: in f32 [K][N] -> out bf16 [N][K] ----
static __device__ void tileT(const float* __restrict__ in, bf16* __restrict__ out,
                             int K, int N, int t, float (*tb)[33]) {
    int nt = N >> 5;
    int bx = (t % nt) << 5, by = (t / nt) << 5;
    int tx = threadIdx.x & 31, r0 = threadIdx.x >> 5;
#pragma unroll
    for (int r = r0; r < 32; r += 8)
        tb[r][tx] = in[(size_t)(by + r) * N + bx + tx];
    __syncthreads();
#pragma unroll
    for (int r = r0; r < 32; r += 8)
        out[(size_t)(bx + r) * K + by + tx] = __float2bfloat16(tb[tx][r]);
}

#define LN_BLKS   T_TOK                       // 2048
#define INW_T     ((N2 / 32) * (DM / 32))     // 4096
#define OUTW_T    ((DM / 32) * (DI / 32))     // 2048
#define MRGW_T    ((DI / 32) * (N2 / 32))     // 8192
#define SMALL_BLK ((2 * XDP_LD * DI + 2 * DI * DTR) / 256)  // 3072

// ---------------- prep_mega: LN + all weight preps ----------------
__global__ __launch_bounds__(256) void prep_mega(const float* __restrict__ x,
                                                 const float* __restrict__ gamma,
                                                 const float* __restrict__ beta,
                                                 bf16* __restrict__ H,
                                                 const float* __restrict__ in_w, bf16* __restrict__ in_wT,
                                                 const float* __restrict__ out_w, bf16* __restrict__ out_wT,
                                                 const float* __restrict__ merge_w, bf16* __restrict__ merge_wT,
                                                 const float* __restrict__ xpf, const float* __restrict__ xpb,
                                                 bf16* __restrict__ XPF, bf16* __restrict__ XPB,
                                                 const float* __restrict__ dtwf, const float* __restrict__ dtwb,
                                                 bf16* __restrict__ dtwT) {
    __shared__ float tbuf[32][33];
    __shared__ float red[8];
    int bid = blockIdx.x;
    int tid = threadIdx.x;

    if (bid < LN_BLKS) {
        // ---- LayerNorm, one token per block ----
        int t = bid;
        float xv[4];
        float s = 0.f, s2 = 0.f;
#pragma unroll
        for (int k = 0; k < 4; ++k) {
            float v = x[(size_t)t * DM + k * 256 + tid];
            xv[k] = v; s += v; s2 += v * v;
        }
#pragma unroll
        for (int off = 32; off; off >>= 1) {
            s  += __shfl_down(s, off);
            s2 += __shfl_down(s2, off);
        }
        int wid = tid >> 6, lane = tid & 63;
        if (!lane) { red[wid] = s; red[4 + wid] = s2; }
        __syncthreads();
        if (tid == 0) {
            float S = red[0] + red[1] + red[2] + red[3];
            float S2 = red[4] + red[5] + red[6] + red[7];
            float mu = S * (1.f / DM);
            float var = S2 * (1.f / DM) - mu * mu;
            red[0] = mu;
            red[1] = rsqrtf(var + 1e-5f);
        }
        __syncthreads();
        float mu = red[0], rs = red[1];
#pragma unroll
        for (int k = 0; k < 4; ++k) {
            int i = k * 256 + tid;
            H[(size_t)t * DM + i] = __float2bfloat16((xv[k] - mu) * rs * gamma[i] + beta[i]);
        }
        return;
    }
    bid -= LN_BLKS;
    if (bid < INW_T)  { tileT(in_w, in_wT, DM, N2, bid, tbuf); return; }
    bid -= INW_T;
    if (bid < OUTW_T) { tileT(out_w, out_wT, DI, DM, bid, tbuf); return; }
    bid -= OUTW_T;
    if (bid < MRGW_T) { tileT(merge_w, merge_wT, N2, DI, bid, tbuf); return; }
    bid -= MRGW_T;
    // small: xproj pad-transpose + dt_w transpose
    int idx = bid * 256 + tid;
    if (idx < 2 * XDP_LD * DI) {
        int dir = idx >= XDP_LD * DI;
        int i = idx - dir * (XDP_LD * DI);
        int n = i >> 11;
        int k = i & (DI - 1);
        float v = (n < XDN) ? (dir ? xpb : xpf)[k * XDN + n] : 0.f;
        (dir ? XPB : XPF)[i] = __float2bfloat16(v);
    } else {
        int j = idx - 2 * XDP_LD * DI;     // over 2*2048*64
        int dir = j >= DI * DTR;
        int e = j - dir * (DI * DTR);
        int n = e >> 6;
        int k = e & 63;
        dtwT[(size_t)dir * DI * DTR + n * DTR + k] =
            __float2bfloat16((dir ? dtwb : dtwf)[(size_t)k * DI + n]);
    }
}

// ---------------- MFMA GEMM: C(MxN) = A(MxK,bf16,row-major) * BT(NxK,bf16)^T ----------------
// 128x128 tile, BK=64, 4 waves each 64x64 (4x4 of 16x16x32 MFMA); split-K over gridDim.z
template <int EPI>
__global__ __launch_bounds__(256) void mfma_gemm(const bf16* __restrict__ A,
                                                 const bf16* __restrict__ BT,
                                                 const bf16* __restrict__ BT2, int bysplit,
                                                 bf16* __restrict__ Cb,
                                                 const float* __restrict__ resid,
                                                 float* __restrict__ outf,
                                                 bf16* __restrict__ Pb,
                                                 const float* __restrict__ bias1,
                                                 const float* __restrict__ bias2,
                                                 int M, int N, int K) {
    __shared__ bf16 As[8192];   // [kg 0..7][m 0..127][8]
    __shared__ bf16 Bs[8192];   // [kg 0..7][n 0..127][8]
    int tid = threadIdx.x;
    int wave = tid >> 6, lane = tid & 63;
    int q = lane >> 4, ln16 = lane & 15;
    int bm = blockIdx.y * 128, bn = blockIdx.x * 128;
    int wm = (wave >> 1) * 64, wn = (wave & 1) * 64;
    const bf16* Bt = ((int)blockIdx.y < bysplit) ? BT : BT2;

    int ks = K / gridDim.z;
    int kb = blockIdx.z * ks;

    f32x4 zf; zf[0] = zf[1] = zf[2] = zf[3] = 0.f;
    f32x4 acc[4][4];
#pragma unroll
    for (int i = 0; i < 4; ++i)
#pragma unroll
        for (int j = 0; j < 4; ++j) acc[i][j] = zf;

    for (int k0 = kb; k0 < kb + ks; k0 += 64) {
#pragma unroll
        for (int i = 0; i < 4; ++i) {
            int s = wave * 256 + i * 64 + lane;   // slot 0..1023
            int kg = s >> 7, m = s & 127;
            gload_lds16(&A[(size_t)(bm + m) * K + k0 + kg * 8], &As[(wave * 256 + i * 64) * 8]);
            gload_lds16(&Bt[(size_t)(bn + m) * K + k0 + kg * 8], &Bs[(wave * 256 + i * 64) * 8]);
        }
        __syncthreads();
#pragma unroll
        for (int kk = 0; kk < 2; ++kk) {
            bf16x8 af[4], bfr[4];
#pragma unroll
            for (int i = 0; i < 4; ++i) {
                af[i]  = *(const bf16x8*)&As[(((kk * 4 + q) * 128) + (wm + i * 16 + ln16)) * 8];
                bfr[i] = *(const bf16x8*)&Bs[(((kk * 4 + q) * 128) + (wn + i * 16 + ln16)) * 8];
            }
#pragma unroll
            for (int i = 0; i < 4; ++i)
#pragma unroll
                for (int j = 0; j < 4; ++j)
                    acc[i][j] = __builtin_amdgcn_mfma_f32_16x16x32_bf16(af[i], bfr[j], acc[i][j], 0, 0, 0);
        }
        __syncthreads();
    }

    size_t pbase = (size_t)blockIdx.z * M * N;
#pragma unroll
    for (int i = 0; i < 4; ++i)
#pragma unroll
        for (int r = 0; r < 4; ++r) {
            int row = bm + wm + i * 16 + q * 4 + r;
            const float* bias = (EPI == 4) ? ((row < T_TOK) ? bias1 : bias2) : nullptr;
#pragma unroll
            for (int j = 0; j < 4; ++j) {
                int col = bn + wn + j * 16 + ln16;
                size_t idx = (size_t)row * N + col;
                float v = acc[i][j][r];
                if (EPI == 0)      Cb[idx] = __float2bfloat16(v);
                else if (EPI == 1) outf[idx] = resid[idx] + v;
                else if (EPI == 2) outf[idx] = v;
                else if (EPI == 3) Pb[pbase + idx] = __float2bfloat16(v);
                else {
                    Cb[idx] = __float2bfloat16(softplus_fast(v + bias[col]));
                }
            }
        }
}

// ---------------- gemm256: 256x256 tile, 8 waves, BK=32, quad-buffered LDS ----------------
// R3 register-pipelined structure (best measured: 41.6-42.0us merge) + bijective XCD
// swizzle (FETCH 73.8->24.6 MB, R5). Reverted here after R8's faithful-8-phase test
// came back neutral-negative: all schedule shapes plateau ~30% MfmaUtil at 1 block/CU.
// Register-pipelined single phase per K-tile: iter t reads frags(t+1) into the idle reg
// set BEFORE MFMA(t); one raw s_barrier per K-tile; stage(t+3) issued at iter t with
// end-of-iter counted vmcnt(4) confirming S(t+2).
// Races: stage(t+3) writes buf(t-1)&3, whose frag reads drained before barrier(t-1).
// Requires NT even, NT>=4. EPI 0: bf16 store to Cb. EPI 3: partial to Pb + z*M*N.
template <int EPI>
__global__ __launch_bounds__(512, 2) void gemm256(const bf16* __restrict__ A,
                                                  const bf16* __restrict__ BT,
                                                  bf16* __restrict__ Cb,
                                                  bf16* __restrict__ Pb,
                                                  int M, int N, int K) {
    __shared__ bf16 LA[4][8192];   // per buf: 256 rows x 32 k (64B rows), swizzled
    __shared__ bf16 LB[4][8192];
    int tid = threadIdx.x;
    int wave = tid >> 6, lane = tid & 63;
    int q = lane >> 4, ln16 = lane & 15;

    // ---- bijective XCD swizzle (m204): hardware linear id -> tile id ----
    int gx = gridDim.x, gy = gridDim.y, gz = gridDim.z;
    int L = blockIdx.x + gx * (blockIdx.y + gy * blockIdx.z);
    int nwg = gx * gy * gz;
    int qd = nwg >> 3, rd = nwg & 7;
    int xcd = L & 7, base = L >> 3;
    int wg = (xcd < rd ? xcd * (qd + 1) : rd * (qd + 1) + (xcd - rd) * qd) + base;
    int bxi = wg % gx, byi = (wg / gx) % gy, bzi = wg / (gx * gy);

    int bm = byi * 256, bn = bxi * 256;
    int wm = (wave >> 2) * 128, wn = (wave & 3) * 64;
    int ksz = K / gz;
    int kb = bzi * ksz;
    int NT = ksz >> 5;             // K-tiles of 32; NT even, >= 4

    // staging: 2 loads per matrix per K-tile; load l covers LDS bytes [l*8192, l*8192+8192)
    // LDS[x] holds element at swz(x); swz(o) = o ^ (((o>>7)&3)<<4)  (involution, 16B-preserving)
    int o0 = tid * 16, o1 = 8192 + tid * 16;
    int r0 = o0 >> 6, r1 = o1 >> 6;
    int c0 = (o0 & 63) ^ (((r0 >> 1) & 3) << 4);
    int c1 = (o1 & 63) ^ (((r1 >> 1) & 3) << 4);
    const bf16* pa0 = &A[(size_t)(bm + r0) * K + kb + (c0 >> 1)];
    const bf16* pa1 = &A[(size_t)(bm + r1) * K + kb + (c1 >> 1)];
    const bf16* pb0 = &BT[(size_t)(bn + r0) * K + kb + (c0 >> 1)];
    const bf16* pb1 = &BT[(size_t)(bn + r1) * K + kb + (c1 >> 1)];
    int d0 = wave * 512;           // element index of wave-uniform LDS dest, load 0
    int d1 = 4096 + wave * 512;    // load 1

    // fragment LDS byte offsets (swizzled), constant across K-tiles
    int aoff[8], boff[4];
#pragma unroll
    for (int i = 0; i < 8; ++i) {
        int r = wm + i * 16 + ln16;
        aoff[i] = (r * 64 + q * 16) ^ (((r >> 1) & 3) << 4);
    }
#pragma unroll
    for (int j = 0; j < 4; ++j) {
        int r = wn + j * 16 + ln16;
        boff[j] = (r * 64 + q * 16) ^ (((r >> 1) & 3) << 4);
    }

    f32x4 zf; zf[0] = zf[1] = zf[2] = zf[3] = 0.f;
    f32x4 acc[8][4];
#pragma unroll
    for (int i = 0; i < 8; ++i)
#pragma unroll
        for (int j = 0; j < 4; ++j) acc[i][j] = zf;

    auto STAGE = [&](int b, int koff) {
        gload_lds16(pa0 + koff, &LA[b][d0]);
        gload_lds16(pa1 + koff, &LA[b][d1]);
        gload_lds16(pb0 + koff, &LB[b][d0]);
        gload_lds16(pb1 + koff, &LB[b][d1]);
    };

#define RD_FRAGS(AV, BV, TT) do {                                             \
        const bf16* LAb_ = LA[(TT) & 3];                                      \
        const bf16* LBb_ = LB[(TT) & 3];                                      \
        _Pragma("unroll")                                                     \
        for (int j_ = 0; j_ < 4; ++j_) BV[j_] = *(const bf16x8*)&LBb_[boff[j_] >> 1]; \
        _Pragma("unroll")                                                     \
        for (int i_ = 0; i_ < 8; ++i_) AV[i_] = *(const bf16x8*)&LAb_[aoff[i_] >> 1]; \
    } while (0)

#define MFMA_ALL(AV, BV) do {                                                 \
        __builtin_amdgcn_s_setprio(1);                                        \
        _Pragma("unroll")                                                     \
        for (int i_ = 0; i_ < 8; ++i_)                                        \
            _Pragma("unroll")                                                 \
            for (int j_ = 0; j_ < 4; ++j_)                                    \
                acc[i_][j_] = __builtin_amdgcn_mfma_f32_16x16x32_bf16(AV[i_], BV[j_], acc[i_][j_], 0, 0, 0); \
        __builtin_amdgcn_s_setprio(0);                                        \
    } while (0)

    bf16x8 avX[8], bvX[4], avY[8], bvY[4];

    // prologue: stage K-tiles 0..2 (12 loads); wait tiles 0,1 (vmcnt(4) leaves S2); barrier
    STAGE(0, 0); STAGE(1, 32); STAGE(2, 64);
    asm volatile("s_waitcnt vmcnt(4)" ::: "memory");
    SBAR();
    RD_FRAGS(avX, bvX, 0);

    for (int t = 0; t < NT; t += 2) {
        // ---- even iter t: MFMA on X, prefetch frags(t+1) into Y ----
        if (t + 1 < NT) RD_FRAGS(avY, bvY, t + 1);
        if (t + 3 < NT) STAGE((t + 3) & 3, (t + 3) * 32);
        MFMA_ALL(avX, bvX);
        if (t + 3 < NT)      asm volatile("s_waitcnt vmcnt(4)" ::: "memory");
        else if (t + 2 < NT) asm volatile("s_waitcnt vmcnt(0)" ::: "memory");
        SBAR();
        // ---- odd iter t+1: MFMA on Y, prefetch frags(t+2) into X ----
        if (t + 2 < NT) RD_FRAGS(avX, bvX, t + 2);
        if (t + 4 < NT) STAGE((t + 4) & 3, (t + 4) * 32);
        MFMA_ALL(avY, bvY);
        if (t + 4 < NT)      asm volatile("s_waitcnt vmcnt(4)" ::: "memory");
        else if (t + 3 < NT) asm volatile("s_waitcnt vmcnt(0)" ::: "memory");
        SBAR();
    }
#undef RD_FRAGS
#undef MFMA_ALL

    size_t pbase = (size_t)bzi * ((size_t)M * N);
#pragma unroll
    for (int i = 0; i < 8; ++i)
#pragma unroll
        for (int r = 0; r < 4; ++r) {
            int row = bm + wm + i * 16 + q * 4 + r;
#pragma unroll
            for (int j = 0; j < 4; ++j) {
                int col = bn + wn + j * 16 + ln16;
                size_t idx = (size_t)row * N + col;
                float v = acc[i][j][r];
                if (EPI == 0) Cb[idx] = __float2bfloat16(v);
                else          Pb[pbase + idx] = __float2bfloat16(v);
            }
        }
}

// ---------------- split-K reduce kernels (bf16 partials) ----------------
__global__ __launch_bounds__(256) void reduce_plain(const bf16* __restrict__ P, int ns, size_t MN,
                                                    bf16* __restrict__ O) {
    size_t i = ((size_t)blockIdx.x * 256 + threadIdx.x) * 4;
    float s[4] = {0.f, 0.f, 0.f, 0.f};
    for (int k = 0; k < ns; ++k) {
        ushort4 p = *reinterpret_cast<const ushort4*>(&P[(size_t)k * MN + i]);
        s[0] += bits2f(p.x); s[1] += bits2f(p.y); s[2] += bits2f(p.z); s[3] += bits2f(p.w);
    }
    bf16 r[4];
#pragma unroll
    for (int j = 0; j < 4; ++j) r[j] = __float2bfloat16(s[j]);
    *reinterpret_cast<ushort4*>(&O[i]) = *reinterpret_cast<ushort4*>(r);
}

__global__ __launch_bounds__(256) void reduce_gate(const bf16* __restrict__ P, int ns, size_t MN,
                                                   const bf16* __restrict__ XZ, bf16* __restrict__ YM) {
    size_t i = ((size_t)blockIdx.x * 256 + threadIdx.x) * 4;  // over T_TOK*DI
    float s[4] = {0.f, 0.f, 0.f, 0.f};
    for (int k = 0; k < ns; ++k) {
        ushort4 p = *reinterpret_cast<const ushort4*>(&P[(size_t)k * MN + i]);
        s[0] += bits2f(p.x); s[1] += bits2f(p.y); s[2] += bits2f(p.z); s[3] += bits2f(p.w);
    }
    int t = (int)(i >> 11), c = (int)(i & (DI - 1));
    const bf16* zp = &XZ[(size_t)t * N2 + DI + c];
    bf16 r[4];
#pragma unroll
    for (int j = 0; j < 4; ++j) {
        float z = b2f(zp[j]);
        r[j] = __float2bfloat16(s[j] * (z / (1.f + __expf(-z))));
    }
    *reinterpret_cast<ushort4*>(&YM[i]) = *reinterpret_cast<ushort4*>(r);
}

__global__ __launch_bounds__(256) void reduce_out(const bf16* __restrict__ P, int ns, size_t MN,
                                                  const float* __restrict__ x, float* __restrict__ out) {
    size_t i = ((size_t)blockIdx.x * 256 + threadIdx.x) * 4;  // over T_TOK*DM
    float s[4] = {0.f, 0.f, 0.f, 0.f};
    for (int k = 0; k < ns; ++k) {
        ushort4 p = *reinterpret_cast<const ushort4*>(&P[(size_t)k * MN + i]);
        s[0] += bits2f(p.x); s[1] += bits2f(p.y); s[2] += bits2f(p.z); s[3] += bits2f(p.w);
    }
    float4 xv = *reinterpret_cast<const float4*>(&x[i]);
    float4 o = {s[0] + xv.x, s[1] + xv.y, s[2] + xv.z, s[3] + xv.w};
    *reinterpret_cast<float4*>(&out[i]) = o;
}

__global__ __launch_bounds__(256) void reduce_xdbl(const bf16* __restrict__ P, int ns, size_t MN,
                                                   float* __restrict__ XDP, bf16* __restrict__ XDdt) {
    size_t i = ((size_t)blockIdx.x * 256 + threadIdx.x) * 4;  // over 2*T_TOK*128
    float s[4] = {0.f, 0.f, 0.f, 0.f};
    for (int k = 0; k < ns; ++k) {
        ushort4 p = *reinterpret_cast<const ushort4*>(&P[(size_t)k * MN + i]);
        s[0] += bits2f(p.x); s[1] += bits2f(p.y); s[2] += bits2f(p.z); s[3] += bits2f(p.w);
    }
    float4 o = {s[0], s[1], s[2], s[3]};
    *reinterpret_cast<float4*>(&XDP[i]) = o;
    int col = (int)(i & (XDP_LD - 1));
    if (col < DTR) {
        size_t row = i >> 7;
        bf16 r[4];
#pragma unroll
        for (int j = 0; j < 4; ++j) r[j] = __float2bfloat16(s[j]);
        *reinterpret_cast<ushort4*>(&XDdt[row * DTR + col]) = *reinterpret_cast<ushort4*>(r);
    }
}

// ---------------- dt GEMM fallback (vector, K=64, reads XDP fp32) ----------------
__global__ __launch_bounds__(256) void gemm_dt(const float* __restrict__ A,   // lda=128
                                               const float* __restrict__ Bw,  // 64 x 2048 f32
                                               const float* __restrict__ bias,
                                               bf16* __restrict__ Cb, int M, int N) {
    __shared__ float As[16][68];
    __shared__ float Bs[16][68];
    int tid = threadIdx.x;
    int bm = blockIdx.y * 64, bn = blockIdx.x * 64;
    int tx = tid & 15, ty = tid >> 4;
    float acc[4][4];
#pragma unroll
    for (int i = 0; i < 4; ++i)
#pragma unroll
        for (int j = 0; j < 4; ++j) acc[i][j] = 0.f;
    int arow = tid >> 2, acg = (tid & 3) * 4;
    int brow = tid >> 4, bcol = (tid & 15) * 4;
    for (int k0 = 0; k0 < DTR; k0 += 16) {
        float4 av = *reinterpret_cast<const float4*>(&A[(size_t)(bm + arow) * XDP_LD + k0 + acg]);
        As[acg + 0][arow] = av.x; As[acg + 1][arow] = av.y;
        As[acg + 2][arow] = av.z; As[acg + 3][arow] = av.w;
        float4 bv = *reinterpret_cast<const float4*>(&Bw[(size_t)(k0 + brow) * N + bn + bcol]);
        Bs[brow][bcol + 0] = bv.x; Bs[brow][bcol + 1] = bv.y;
        Bs[brow][bcol + 2] = bv.z; Bs[brow][bcol + 3] = bv.w;
        __syncthreads();
#pragma unroll
        for (int kk = 0; kk < 16; ++kk) {
            float4 a = *reinterpret_cast<const float4*>(&As[kk][ty * 4]);
            float4 b = *reinterpret_cast<const float4*>(&Bs[kk][tx * 4]);
            acc[0][0] += a.x * b.x; acc[0][1] += a.x * b.y; acc[0][2] += a.x * b.z; acc[0][3] += a.x * b.w;
            acc[1][0] += a.y * b.x; acc[1][1] += a.y * b.y; acc[1][2] += a.y * b.z; acc[1][3] += a.y * b.w;
            acc[2][0] += a.z * b.x; acc[2][1] += a.z * b.y; acc[2][2] += a.z * b.z; acc[2][3] += a.z * b.w;
            acc[3][0] += a.w * b.x; acc[3][1] += a.w * b.y; acc[3][2] += a.w * b.z; acc[3][3] += a.w * b.w;
        }
        __syncthreads();
    }
    int row0 = bm + ty * 4, col0 = bn + tx * 4;
#pragma unroll
    for (int i = 0; i < 4; ++i)
#pragma unroll
        for (int j = 0; j < 4; ++j) {
            float v = acc[i][j] + bias[col0 + j];
            Cb[(size_t)(row0 + i) * N + col0 + j] = __float2bfloat16(softplus_fast(v));
        }
}

// ---------------- depthwise causal conv (fwd) + anti-causal (bwd) + SiLU ----------------
__global__ __launch_bounds__(256) void conv_kernel(const bf16* __restrict__ XZ,
                                                   const float* __restrict__ wf, const float* __restrict__ bf_,
                                                   const float* __restrict__ wb, const float* __restrict__ bb_,
                                                   bf16* __restrict__ XCF, bf16* __restrict__ XCB) {
    int idx = blockIdx.x * 256 + threadIdx.x;   // over T_TOK*DI
    int c = idx & (DI - 1);
    int g = idx >> 11;
    int l = g & (SEQ - 1);
    int b = g >> 10;
    float sf = bf_[c];
    float sb = bb_[c];
#pragma unroll
    for (int j = 0; j < 4; ++j) {
        int lf = l - 3 + j;
        if (lf >= 0) sf += wf[c * 4 + j] * b2f(XZ[((size_t)(b * SEQ + lf)) * N2 + c]);
        int lb = l + 3 - j;
        if (lb < SEQ) sb += wb[c * 4 + j] * b2f(XZ[((size_t)(b * SEQ + lb)) * N2 + c]);
    }
    XCF[idx] = __float2bfloat16(sf / (1.f + __expf(-sf)));
    XCB[idx] = __float2bfloat16(sb / (1.f + __expf(-sb)));
}

// ---------------- chunked selective scan (3 kernels, HW stream barriers) ----------------
// Templated on NC (chunks per sequence); CLEN = SEQ/NC. 2 threads per channel
// (8 states each); DT/XC tiles bulk-staged into LDS via bf16x8 coalesced loads.
// NC=64 halves the per-wave serial chain and doubles blocks (4096 -> 32-wave/CU cap);
// runtime fallback to NC=32 if workspace can't hold the larger HLOC.
template <int NC, bool FINAL>
__global__ __launch_bounds__(256) void scan_chunk(const bf16* __restrict__ DTF_, const bf16* __restrict__ DTB_,
                                                  const bf16* __restrict__ XCF_, const bf16* __restrict__ XCB_,
                                                  const float* __restrict__ XDP,
                                                  const float* __restrict__ Af, const float* __restrict__ Ab,
                                                  const float* __restrict__ Df, const float* __restrict__ Db,
                                                  float* __restrict__ HLOC, float* __restrict__ SUMDT,
                                                  bf16* __restrict__ YCAT) {
    constexpr int CL = SEQ / NC;
    __shared__ float bsl[CL][32];
    __shared__ bf16 dtl[CL][128];
    __shared__ bf16 xcl[CL][128];
    int tid = threadIdx.x;
    int sg = tid & 1;                          // state group: states sg*8 .. sg*8+7
    int cl = tid >> 1;                         // channel local 0..127
    int cbase = blockIdx.x * 128;
    int c = cbase + cl;
    int b = blockIdx.y;
    int dir = (int)blockIdx.z >= NC;
    int chunk = blockIdx.z - dir * NC;
    const bf16* DT = dir ? DTB_ : DTF_;
    const bf16* XC = dir ? XCB_ : XCF_;
    // stage B/C rows for the whole chunk: CL tokens x 32 floats
    for (int i = tid; i < CL * 8; i += 256) {
        int it = i >> 3, j4 = (i & 7) * 4;
        int sit = chunk * CL + it;
        int l = dir ? (SEQ - 1 - sit) : sit;
        size_t row = (size_t)dir * T_TOK + (size_t)b * SEQ + l;
        *(float4*)&bsl[it][j4] = *(const float4*)&XDP[row * XDP_LD + DTR + j4];
    }
    // stage DT/XC tiles: CL tokens x 128 channels, 16B chunks, fully coalesced
    for (int ch = tid; ch < CL * 16; ch += 256) {
        int it = ch >> 4, of = (ch & 15) * 8;
        int sit = chunk * CL + it;
        int l = dir ? (SEQ - 1 - sit) : sit;
        size_t g = (size_t)b * SEQ + l;
        *(bf16x8*)&dtl[it][of] = *(const bf16x8*)&DT[g * DI + cbase + of];
        *(bf16x8*)&xcl[it][of] = *(const bf16x8*)&XC[g * DI + cbase + of];
    }
    const float* Al = dir ? Ab : Af;
    float A[8];
#pragma unroll
    for (int n = 0; n < 8; ++n) A[n] = -__expf(Al[c * NST + sg * 8 + n]);
    size_t base = ((((size_t)dir * BATCH + b) * NC + chunk) * DI + c);
    float h[8];
    float Dv = 0.f;
    if (FINAL) {
#pragma unroll
        for (int n = 0; n < 8; ++n) h[n] = HLOC[base * NST + sg * 8 + n];
        Dv = (dir ? Db : Df)[c];
    } else {
#pragma unroll
        for (int n = 0; n < 8; ++n) h[n] = 0.f;
    }
    __syncthreads();
    float sumdt = 0.f;
    for (int it = 0; it < CL; ++it) {
        int sit = chunk * CL + it;
        int l = dir ? (SEQ - 1 - sit) : sit;
        size_t g = (size_t)b * SEQ + l;
        float dt = b2f(dtl[it][cl]);
        float xc = b2f(xcl[it][cl]);
        float dtxc = dt * xc;
        const float* bs = &bsl[it][sg * 8];
        if (FINAL) {
            float y = 0.f;
#pragma unroll
            for (int n = 0; n < 8; ++n) {
                h[n] = __expf(dt * A[n]) * h[n] + dtxc * bs[n];
                y += h[n] * bs[NST + n];
            }
            y += __shfl_xor(y, 1);
            if (!sg) YCAT[g * N2 + dir * DI + c] = __float2bfloat16(y + xc * Dv);
        } else {
            sumdt += dt;
#pragma unroll
            for (int n = 0; n < 8; ++n)
                h[n] = __expf(dt * A[n]) * h[n] + dtxc * bs[n];
        }
    }
    if (!FINAL) {
#pragma unroll
        for (int n = 0; n < 8; ++n) HLOC[base * NST + sg * 8 + n] = h[n];
        if (!sg) SUMDT[base] = sumdt;
    }
}

// phase B: sequential combine over chunks; rewrites HLOC[k] with carry-in h for chunk k
__global__ __launch_bounds__(256) void scan_combine(float* __restrict__ HLOC,
                                                    const float* __restrict__ SUMDT,
                                                    const float* __restrict__ Af,
                                                    const float* __restrict__ Ab, int nchunk) {
    int idx = blockIdx.x * 256 + threadIdx.x;   // over 2*BATCH*DI*NST = 131072
    int n = idx & 15;
    int c = (idx >> 4) & (DI - 1);
    int b = (idx >> 15) & 1;
    int dir = idx >> 16;
    float A = -__expf((dir ? Ab : Af)[c * NST + n]);
    float h = 0.f;
    for (int k = 0; k < nchunk; ++k) {
        size_t base = ((((size_t)dir * BATCH + b) * nchunk + k) * DI + c);
        float P = __expf(A * SUMDT[base]);
        float hl = HLOC[base * NST + n];
        HLOC[base * NST + n] = h;
        h = P * h + hl;
    }
}

// ---------------- gating fallback: YM *= silu(z) ----------------
__global__ __launch_bounds__(256) void gate_kernel(bf16* __restrict__ YM, const bf16* __restrict__ XZ) {
    int idx = blockIdx.x * 256 + threadIdx.x;  // over T_TOK*DI
    int t = idx >> 11;
    int c = idx & (DI - 1);
    float z = b2f(XZ[(size_t)t * N2 + DI + c]);
    float y = b2f(YM[idx]);
    YM[idx] = __float2bfloat16(y * (z / (1.f + __expf(-z))));
}

extern "C" void kernel_launch(void* const* d_in, const int* in_sizes, int n_in,
                              void* d_out, int out_size, void* d_ws, size_t ws_size,
                              hipStream_t stream) {
    const float* x       = (const float*)d_in[0];
    const float* gamma   = (const float*)d_in[1];
    const float* beta    = (const float*)d_in[2];
    const float* in_w    = (const float*)d_in[3];
    const float* conv_w  = (const float*)d_in[4];
    const float* conv_b  = (const float*)d_in[5];
    const float* xproj_w = (const float*)d_in[6];
    const float* dt_w    = (const float*)d_in[7];
    const float* dt_b    = (const float*)d_in[8];
    const float* A_log   = (const float*)d_in[9];
    const float* D_skip  = (const float*)d_in[10];
    const float* conv_w_b  = (const float*)d_in[11];
    const float* conv_b_b  = (const float*)d_in[12];
    const float* xproj_w_b = (const float*)d_in[13];
    const float* dt_w_b    = (const float*)d_in[14];
    const float* dt_b_b    = (const float*)d_in[15];
    const float* A_log_b   = (const float*)d_in[16];
    const float* D_skip_b  = (const float*)d_in[17];
    const float* merge_w   = (const float*)d_in[18];
    const float* out_w     = (const float*)d_in[19];
    float* out = (float*)d_out;

    // ---- base workspace layout ----
    char* w = (char*)d_ws;
    size_t off = 0;
    bf16* H       = (bf16*)(w + off); off += (size_t)T_TOK * DM * 2;          //  4.19 MB
    bf16* XZ      = (bf16*)(w + off); off += (size_t)T_TOK * N2 * 2;          // 16.78 MB
    bf16* XCF     = (bf16*)(w + off); off += (size_t)T_TOK * DI * 2;          //  8.39 MB
    bf16* XCB     = (bf16*)(w + off); off += (size_t)T_TOK * DI * 2;          //  8.39 MB
    bf16* XPF     = (bf16*)(w + off); off += (size_t)XDP_LD * DI * 2;         //  0.52 MB
    bf16* XPB     = (bf16*)(w + off); off += (size_t)XDP_LD * DI * 2;         //  0.52 MB
    float* XDP    = (float*)(w + off); off += (size_t)2 * T_TOK * XDP_LD * 4; //  2.10 MB
    bf16* DTF     = (bf16*)(w + off); off += (size_t)T_TOK * DI * 2;          //  8.39 MB
    bf16* DTB     = (bf16*)(w + off); off += (size_t)T_TOK * DI * 2;          //  8.39 MB (contig after DTF)
    bf16* YCAT    = (bf16*)(w + off); off += (size_t)T_TOK * N2 * 2;          // 16.78 MB
    bf16* in_wT   = (bf16*)(w + off); off += (size_t)N2 * DM * 2;             //  8.39 MB
    bf16* out_wT  = (bf16*)(w + off); off += (size_t)DM * DI * 2;             //  4.19 MB
    bf16* merge_wT= (bf16*)(w + off); off += (size_t)DI * N2 * 2;             // 16.78 MB
    bf16* dtwT    = (bf16*)(w + off); off += (size_t)2 * DI * DTR * 2;        //  0.52 MB
    bf16* XDdt    = (bf16*)(w + off); off += (size_t)2 * T_TOK * DTR * 2;     //  0.52 MB
    // PART region: time-shared {xz partials | xdbl partials | HLOC+SUMDT | merge partials | out partials}
    char* PART = w + off;
    size_t avail = (ws_size > off) ? ws_size - off : 0;

    // scan chunking: NC=64 if HLOC+SUMDT fit, else NC=32
    size_t need64 = (size_t)2 * BATCH * 64 * DI * NST * 4 + (size_t)2 * BATCH * 64 * DI * 4;
    int nchunk = (avail >= need64) ? 64 : 32;
    float* HLOC  = (float*)PART;
    float* SUMDT = (float*)(PART + (size_t)2 * BATCH * nchunk * DI * NST * 4);
    bf16* Pb     = (bf16*)PART;                                               // split-K bf16 partials
    bf16* YM     = DTF;    // alias: DTF dead after scan C

    size_t MNm = (size_t)T_TOK * DI;          // merge partial elems
    size_t MNo = (size_t)T_TOK * DM;          // out partial elems
    size_t MNx = (size_t)2 * T_TOK * XDP_LD;  // xdbl partial elems
    size_t MNz = (size_t)T_TOK * N2;          // xz partial elems
    int s_merge = (avail >= 4 * MNm * 2) ? 4 : (avail >= 2 * MNm * 2) ? 2 : 0;
    int s_out   = (avail >= 4 * MNo * 2) ? 4 : (avail >= 2 * MNo * 2) ? 2 : 0;
    int s_xdbl  = (avail >= 16 * MNx * 2) ? 16 : (avail >= 8 * MNx * 2) ? 8 : (avail >= 4 * MNx * 2) ? 4 : 0;
    int s_xz    = (avail >= 2 * MNz * 2) ? 2 : 0;

    // 1. mega prep: LN + in_wT + out_wT + merge_wT + xproj/dtw
    prep_mega<<<LN_BLKS + INW_T + OUTW_T + MRGW_T + SMALL_BLK, 256, 0, stream>>>(
        x, gamma, beta, H, in_w, in_wT, out_w, out_wT, merge_w, merge_wT,
        xproj_w, xproj_w_b, XPF, XPB, dt_w, dt_w_b, dtwT);
    // 2. xz = H @ in_w  (M=2048, N=4096, K=1024) -> XZ bf16
    if (s_xz) {
        gemm256<3><<<dim3(N2 / 256, T_TOK / 256, s_xz), 512, 0, stream>>>(
            H, in_wT, nullptr, Pb, T_TOK, N2, DM);
        reduce_plain<<<(int)(MNz / 4 / 256), 256, 0, stream>>>(Pb, s_xz, MNz, XZ);
    } else {
        mfma_gemm<0><<<dim3(N2 / 128, T_TOK / 128), 256, 0, stream>>>(
            H, in_wT, in_wT, 1 << 30, XZ, nullptr, nullptr, nullptr, nullptr, nullptr, T_TOK, N2, DM);
    }
    // 3. depthwise conv + silu, both dirs
    conv_kernel<<<(T_TOK * DI) / 256, 256, 0, stream>>>(XZ, conv_w, conv_b, conv_w_b, conv_b_b, XCF, XCB);
    // 4. x_dbl (padded): XDP = [XCF;XCB] @ xproj (M=4096, N=128, K=2048), B per dir
    if (s_xdbl) {
        mfma_gemm<3><<<dim3(1, (2 * T_TOK) / 128, s_xdbl), 256, 0, stream>>>(
            XCF, XPF, XPB, (T_TOK / 128), nullptr, nullptr, nullptr, Pb, nullptr, nullptr,
            2 * T_TOK, XDP_LD, DI);
        reduce_xdbl<<<(int)(MNx / 4 / 256), 256, 0, stream>>>(Pb, s_xdbl, MNx, XDP, XDdt);
        // 5. dt = softplus(XDdt @ dt_w + dt_b) via MFMA (M=4096 both dirs, N=2048, K=64)
        mfma_gemm<4><<<dim3(DI / 128, (2 * T_TOK) / 128), 256, 0, stream>>>(
            XDdt, dtwT, dtwT + (size_t)DI * DTR, (T_TOK / 128), DTF, nullptr, nullptr, nullptr,
            dt_b, dt_b_b, 2 * T_TOK, DI, DTR);
    } else {
        mfma_gemm<2><<<dim3(1, (2 * T_TOK) / 128), 256, 0, stream>>>(
            XCF, XPF, XPB, (T_TOK / 128), nullptr, nullptr, XDP, nullptr, nullptr, nullptr,
            2 * T_TOK, XDP_LD, DI);
        gemm_dt<<<dim3(DI / 64, T_TOK / 64), 256, 0, stream>>>(XDP, dt_w, dt_b, DTF, T_TOK, DI);
        gemm_dt<<<dim3(DI / 64, T_TOK / 64), 256, 0, stream>>>(XDP + (size_t)T_TOK * XDP_LD, dt_w_b, dt_b_b, DTB, T_TOK, DI);
    }
    // 6-8. chunked scan (3 kernels; stream boundaries are the grid barriers)
    if (nchunk == 64) {
        scan_chunk<64, false><<<dim3(DI / 128, BATCH, 128), 256, 0, stream>>>(
            DTF, DTB, XCF, XCB, XDP, A_log, A_log_b, D_skip, D_skip_b, HLOC, SUMDT, YCAT);
        scan_combine<<<(2 * BATCH * DI * NST) / 256, 256, 0, stream>>>(HLOC, SUMDT, A_log, A_log_b, 64);
        scan_chunk<64, true><<<dim3(DI / 128, BATCH, 128), 256, 0, stream>>>(
            DTF, DTB, XCF, XCB, XDP, A_log, A_log_b, D_skip, D_skip_b, HLOC, SUMDT, YCAT);
    } else {
        scan_chunk<32, false><<<dim3(DI / 128, BATCH, 64), 256, 0, stream>>>(
            DTF, DTB, XCF, XCB, XDP, A_log, A_log_b, D_skip, D_skip_b, HLOC, SUMDT, YCAT);
        scan_combine<<<(2 * BATCH * DI * NST) / 256, 256, 0, stream>>>(HLOC, SUMDT, A_log, A_log_b, 32);
        scan_chunk<32, true><<<dim3(DI / 128, BATCH, 64), 256, 0, stream>>>(
            DTF, DTB, XCF, XCB, XDP, A_log, A_log_b, D_skip, D_skip_b, HLOC, SUMDT, YCAT);
    }
    // 9. YM = silu(z) * (YCAT @ merge_w) (M=2048, N=2048, K=4096)
    if (s_merge) {
        gemm256<3><<<dim3(DI / 256, T_TOK / 256, s_merge), 512, 0, stream>>>(
            YCAT, merge_wT, nullptr, Pb, T_TOK, DI, N2);
        reduce_gate<<<(int)(MNm / 4 / 256), 256, 0, stream>>>(Pb, s_merge, MNm, XZ, YM);
    } else {
        mfma_gemm<0><<<dim3(DI / 128, T_TOK / 128), 256, 0, stream>>>(
            YCAT, merge_wT, merge_wT, 1 << 30, YM, nullptr, nullptr, nullptr, nullptr, nullptr,
            T_TOK, DI, N2);
        gate_kernel<<<(T_TOK * DI) / 256, 256, 0, stream>>>(YM, XZ);
    }
    // 10. out = x + YM @ out_w (M=2048, N=1024, K=2048), f32
    if (s_out) {
        mfma_gemm<3><<<dim3(DM / 128, T_TOK / 128, s_out), 256, 0, stream>>>(
            YM, out_wT, out_wT, 1 << 30, nullptr, nullptr, nullptr, Pb, nullptr, nullptr,
            T_TOK, DM, DI);
        reduce_out<<<(int)(MNo / 4 / 256), 256, 0, stream>>>(Pb, s_out, MNo, x, out);
    } else {
        mfma_gemm<1><<<dim3(DM / 128, T_TOK / 128), 256, 0, stream>>>(
            YM, out_wT, out_wT, 1 << 30, nullptr, x, out, nullptr, nullptr, nullptr,
            T_TOK, DM, DI);
    }
}

// Round 10
// 398.291 us; speedup vs baseline: 1.0256x; 1.0256x over previous
//
#include <hip/hip_runtime.h>
#include <hip/hip_bf16.h>
#include <math.h>

typedef __hip_bfloat16 bf16;
typedef unsigned int u32;
typedef __attribute__((ext_vector_type(8))) short bf16x8;
typedef __attribute__((ext_vector_type(4))) float f32x4;

#define BATCH 2
#define SEQ 1024
#define DM 1024
#define DI 2048
#define NST 16
#define DTR 64
#define XDN 96          // dt_rank + 2*N = 64+32
#define XDP_LD 128      // padded x_dbl row
#define T_TOK 2048      // BATCH*SEQ
#define N2 4096         // 2*DI
#define NCHUNK 32
#define CLEN 32

static __device__ __forceinline__ float b2f(bf16 v) { return __bfloat162float(v); }
static __device__ __forceinline__ float bits2f(unsigned short u) {
    return __uint_as_float(((unsigned)u) << 16);
}

// fast softplus: 2 HW transcendentals instead of libm log1pf (branchy, ~5x VALU)
static __device__ __forceinline__ float softplus_fast(float t) {
    return (t > 20.f) ? t : __logf(1.f + __expf(t));
}

// ---- async global->LDS, 16 bytes per lane; LDS dest must be wave-uniform base ----
static __device__ __forceinline__ void gload_lds16(const void* g, void* l) {
    __builtin_amdgcn_global_load_lds((__attribute__((address_space(1))) u32*)(size_t)g,
                                     (__attribute__((address_space(3))) u32*)l, 16, 0, 0);
}

// compiler memory fence + raw barrier (no vmcnt drain, unlike __syncthreads)
#define SBAR() do { asm volatile("" ::: "memory"); __builtin_amdgcn_s_barrier(); asm volatile("" ::: "memory"); } while (0)

// ---- 32x32 LDS tile transpose helper: in f32 [K][N] -> out bf16 [N][K] ----
static __device__ void tileT(const float* __restrict__ in, bf16* __restrict__ out,
                             int K, int N, int t, float (*tb)[33]) {
    int nt = N >> 5;
    int bx = (t % nt) << 5, by = (t / nt) << 5;
    int tx = threadIdx.x & 31, r0 = threadIdx.x >> 5;
#pragma unroll
    for (int r = r0; r < 32; r += 8)
        tb[r][tx] = in[(size_t)(by + r) * N + bx + tx];
    __syncthreads();
#pragma unroll
    for (int r = r0; r < 32; r += 8)
        out[(size_t)(bx + r) * K + by + tx] = __float2bfloat16(tb[tx][r]);
}

#define LN_BLKS   T_TOK                       // 2048
#define INW_T     ((N2 / 32) * (DM / 32))     // 4096
#define OUTW_T    ((DM / 32) * (DI / 32))     // 2048
#define MRGW_T    ((DI / 32) * (N2 / 32))     // 8192
#define SMALL_BLK ((2 * XDP_LD * DI + 2 * DI * DTR) / 256)  // 3072

// ---------------- prep_mega: LN + all weight preps ----------------
__global__ __launch_bounds__(256) void prep_mega(const float* __restrict__ x,
                                                 const float* __restrict__ gamma,
                                                 const float* __restrict__ beta,
                                                 bf16* __restrict__ H,
                                                 const float* __restrict__ in_w, bf16* __restrict__ in_wT,
                                                 const float* __restrict__ out_w, bf16* __restrict__ out_wT,
                                                 const float* __restrict__ merge_w, bf16* __restrict__ merge_wT,
                                                 const float* __restrict__ xpf, const float* __restrict__ xpb,
                                                 bf16* __restrict__ XPF, bf16* __restrict__ XPB,
                                                 const float* __restrict__ dtwf, const float* __restrict__ dtwb,
                                                 bf16* __restrict__ dtwT) {
    __shared__ float tbuf[32][33];
    __shared__ float red[8];
    int bid = blockIdx.x;
    int tid = threadIdx.x;

    if (bid < LN_BLKS) {
        // ---- LayerNorm, one token per block ----
        int t = bid;
        float xv[4];
        float s = 0.f, s2 = 0.f;
#pragma unroll
        for (int k = 0; k < 4; ++k) {
            float v = x[(size_t)t * DM + k * 256 + tid];
            xv[k] = v; s += v; s2 += v * v;
        }
#pragma unroll
        for (int off = 32; off; off >>= 1) {
            s  += __shfl_down(s, off);
            s2 += __shfl_down(s2, off);
        }
        int wid = tid >> 6, lane = tid & 63;
        if (!lane) { red[wid] = s; red[4 + wid] = s2; }
        __syncthreads();
        if (tid == 0) {
            float S = red[0] + red[1] + red[2] + red[3];
            float S2 = red[4] + red[5] + red[6] + red[7];
            float mu = S * (1.f / DM);
            float var = S2 * (1.f / DM) - mu * mu;
            red[0] = mu;
            red[1] = rsqrtf(var + 1e-5f);
        }
        __syncthreads();
        float mu = red[0], rs = red[1];
#pragma unroll
        for (int k = 0; k < 4; ++k) {
            int i = k * 256 + tid;
            H[(size_t)t * DM + i] = __float2bfloat16((xv[k] - mu) * rs * gamma[i] + beta[i]);
        }
        return;
    }
    bid -= LN_BLKS;
    if (bid < INW_T)  { tileT(in_w, in_wT, DM, N2, bid, tbuf); return; }
    bid -= INW_T;
    if (bid < OUTW_T) { tileT(out_w, out_wT, DI, DM, bid, tbuf); return; }
    bid -= OUTW_T;
    if (bid < MRGW_T) { tileT(merge_w, merge_wT, N2, DI, bid, tbuf); return; }
    bid -= MRGW_T;
    // small: xproj pad-transpose + dt_w transpose
    int idx = bid * 256 + tid;
    if (idx < 2 * XDP_LD * DI) {
        int dir = idx >= XDP_LD * DI;
        int i = idx - dir * (XDP_LD * DI);
        int n = i >> 11;
        int k = i & (DI - 1);
        float v = (n < XDN) ? (dir ? xpb : xpf)[k * XDN + n] : 0.f;
        (dir ? XPB : XPF)[i] = __float2bfloat16(v);
    } else {
        int j = idx - 2 * XDP_LD * DI;     // over 2*2048*64
        int dir = j >= DI * DTR;
        int e = j - dir * (DI * DTR);
        int n = e >> 6;
        int k = e & 63;
        dtwT[(size_t)dir * DI * DTR + n * DTR + k] =
            __float2bfloat16((dir ? dtwb : dtwf)[(size_t)k * DI + n]);
    }
}

// ---------------- MFMA GEMM: C(MxN) = A(MxK,bf16,row-major) * BT(NxK,bf16)^T ----------------
// 128x128 tile, BK=64, 4 waves each 64x64 (4x4 of 16x16x32 MFMA); split-K over gridDim.z
template <int EPI>
__global__ __launch_bounds__(256) void mfma_gemm(const bf16* __restrict__ A,
                                                 const bf16* __restrict__ BT,
                                                 const bf16* __restrict__ BT2, int bysplit,
                                                 bf16* __restrict__ Cb,
                                                 const float* __restrict__ resid,
                                                 float* __restrict__ outf,
                                                 bf16* __restrict__ Pb,
                                                 const float* __restrict__ bias1,
                                                 const float* __restrict__ bias2,
                                                 int M, int N, int K) {
    __shared__ bf16 As[8192];   // [kg 0..7][m 0..127][8]
    __shared__ bf16 Bs[8192];   // [kg 0..7][n 0..127][8]
    int tid = threadIdx.x;
    int wave = tid >> 6, lane = tid & 63;
    int q = lane >> 4, ln16 = lane & 15;
    int bm = blockIdx.y * 128, bn = blockIdx.x * 128;
    int wm = (wave >> 1) * 64, wn = (wave & 1) * 64;
    const bf16* Bt = ((int)blockIdx.y < bysplit) ? BT : BT2;

    int ks = K / gridDim.z;
    int kb = blockIdx.z * ks;

    f32x4 zf; zf[0] = zf[1] = zf[2] = zf[3] = 0.f;
    f32x4 acc[4][4];
#pragma unroll
    for (int i = 0; i < 4; ++i)
#pragma unroll
        for (int j = 0; j < 4; ++j) acc[i][j] = zf;

    for (int k0 = kb; k0 < kb + ks; k0 += 64) {
#pragma unroll
        for (int i = 0; i < 4; ++i) {
            int s = wave * 256 + i * 64 + lane;   // slot 0..1023
            int kg = s >> 7, m = s & 127;
            gload_lds16(&A[(size_t)(bm + m) * K + k0 + kg * 8], &As[(wave * 256 + i * 64) * 8]);
            gload_lds16(&Bt[(size_t)(bn + m) * K + k0 + kg * 8], &Bs[(wave * 256 + i * 64) * 8]);
        }
        __syncthreads();
#pragma unroll
        for (int kk = 0; kk < 2; ++kk) {
            bf16x8 af[4], bfr[4];
#pragma unroll
            for (int i = 0; i < 4; ++i) {
                af[i]  = *(const bf16x8*)&As[(((kk * 4 + q) * 128) + (wm + i * 16 + ln16)) * 8];
                bfr[i] = *(const bf16x8*)&Bs[(((kk * 4 + q) * 128) + (wn + i * 16 + ln16)) * 8];
            }
#pragma unroll
            for (int i = 0; i < 4; ++i)
#pragma unroll
                for (int j = 0; j < 4; ++j)
                    acc[i][j] = __builtin_amdgcn_mfma_f32_16x16x32_bf16(af[i], bfr[j], acc[i][j], 0, 0, 0);
        }
        __syncthreads();
    }

    size_t pbase = (size_t)blockIdx.z * M * N;
#pragma unroll
    for (int i = 0; i < 4; ++i)
#pragma unroll
        for (int r = 0; r < 4; ++r) {
            int row = bm + wm + i * 16 + q * 4 + r;
            const float* bias = (EPI == 4) ? ((row < T_TOK) ? bias1 : bias2) : nullptr;
#pragma unroll
            for (int j = 0; j < 4; ++j) {
                int col = bn + wn + j * 16 + ln16;
                size_t idx = (size_t)row * N + col;
                float v = acc[i][j][r];
                if (EPI == 0)      Cb[idx] = __float2bfloat16(v);
                else if (EPI == 1) outf[idx] = resid[idx] + v;
                else if (EPI == 2) outf[idx] = v;
                else if (EPI == 3) Pb[pbase + idx] = __float2bfloat16(v);
                else {
                    Cb[idx] = __float2bfloat16(softplus_fast(v + bias[col]));
                }
            }
        }
}

// ---------------- gemm256: 256x256 tile, 8 waves, BK=32, quad-buffered LDS ----------------
// R3 register-pipelined structure (best measured: 41.6-42.0us merge on R6/R7 pod) +
// bijective XCD swizzle (FETCH 73.8->24.6 MB, R5). R9's 46.5us on identical code was
// pod/clock variance. Schedule-space converged (~30% MfmaUtil at 1 block/CU): R4 fine
// phases and R8 faithful m201 8-phase both neutral-to-negative.
template <int EPI>
__global__ __launch_bounds__(512, 2) void gemm256(const bf16* __restrict__ A,
                                                  const bf16* __restrict__ BT,
                                                  bf16* __restrict__ Cb,
                                                  bf16* __restrict__ Pb,
                                                  int M, int N, int K) {
    __shared__ bf16 LA[4][8192];   // per buf: 256 rows x 32 k (64B rows), swizzled
    __shared__ bf16 LB[4][8192];
    int tid = threadIdx.x;
    int wave = tid >> 6, lane = tid & 63;
    int q = lane >> 4, ln16 = lane & 15;

    // ---- bijective XCD swizzle (m204): hardware linear id -> tile id ----
    int gx = gridDim.x, gy = gridDim.y, gz = gridDim.z;
    int L = blockIdx.x + gx * (blockIdx.y + gy * blockIdx.z);
    int nwg = gx * gy * gz;
    int qd = nwg >> 3, rd = nwg & 7;
    int xcd = L & 7, base = L >> 3;
    int wg = (xcd < rd ? xcd * (qd + 1) : rd * (qd + 1) + (xcd - rd) * qd) + base;
    int bxi = wg % gx, byi = (wg / gx) % gy, bzi = wg / (gx * gy);

    int bm = byi * 256, bn = bxi * 256;
    int wm = (wave >> 2) * 128, wn = (wave & 3) * 64;
    int ksz = K / gz;
    int kb = bzi * ksz;
    int NT = ksz >> 5;             // K-tiles of 32; NT even, >= 4

    // staging: 2 loads per matrix per K-tile; load l covers LDS bytes [l*8192, l*8192+8192)
    // LDS[x] holds element at swz(x); swz(o) = o ^ (((o>>7)&3)<<4)  (involution, 16B-preserving)
    int o0 = tid * 16, o1 = 8192 + tid * 16;
    int r0 = o0 >> 6, r1 = o1 >> 6;
    int c0 = (o0 & 63) ^ (((r0 >> 1) & 3) << 4);
    int c1 = (o1 & 63) ^ (((r1 >> 1) & 3) << 4);
    const bf16* pa0 = &A[(size_t)(bm + r0) * K + kb + (c0 >> 1)];
    const bf16* pa1 = &A[(size_t)(bm + r1) * K + kb + (c1 >> 1)];
    const bf16* pb0 = &BT[(size_t)(bn + r0) * K + kb + (c0 >> 1)];
    const bf16* pb1 = &BT[(size_t)(bn + r1) * K + kb + (c1 >> 1)];
    int d0 = wave * 512;           // element index of wave-uniform LDS dest, load 0
    int d1 = 4096 + wave * 512;    // load 1

    // fragment LDS byte offsets (swizzled), constant across K-tiles
    int aoff[8], boff[4];
#pragma unroll
    for (int i = 0; i < 8; ++i) {
        int r = wm + i * 16 + ln16;
        aoff[i] = (r * 64 + q * 16) ^ (((r >> 1) & 3) << 4);
    }
#pragma unroll
    for (int j = 0; j < 4; ++j) {
        int r = wn + j * 16 + ln16;
        boff[j] = (r * 64 + q * 16) ^ (((r >> 1) & 3) << 4);
    }

    f32x4 zf; zf[0] = zf[1] = zf[2] = zf[3] = 0.f;
    f32x4 acc[8][4];
#pragma unroll
    for (int i = 0; i < 8; ++i)
#pragma unroll
        for (int j = 0; j < 4; ++j) acc[i][j] = zf;

    auto STAGE = [&](int b, int koff) {
        gload_lds16(pa0 + koff, &LA[b][d0]);
        gload_lds16(pa1 + koff, &LA[b][d1]);
        gload_lds16(pb0 + koff, &LB[b][d0]);
        gload_lds16(pb1 + koff, &LB[b][d1]);
    };

#define RD_FRAGS(AV, BV, TT) do {                                             \
        const bf16* LAb_ = LA[(TT) & 3];                                      \
        const bf16* LBb_ = LB[(TT) & 3];                                      \
        _Pragma("unroll")                                                     \
        for (int j_ = 0; j_ < 4; ++j_) BV[j_] = *(const bf16x8*)&LBb_[boff[j_] >> 1]; \
        _Pragma("unroll")                                                     \
        for (int i_ = 0; i_ < 8; ++i_) AV[i_] = *(const bf16x8*)&LAb_[aoff[i_] >> 1]; \
    } while (0)

#define MFMA_ALL(AV, BV) do {                                                 \
        __builtin_amdgcn_s_setprio(1);                                        \
        _Pragma("unroll")                                                     \
        for (int i_ = 0; i_ < 8; ++i_)                                        \
            _Pragma("unroll")                                                 \
            for (int j_ = 0; j_ < 4; ++j_)                                    \
                acc[i_][j_] = __builtin_amdgcn_mfma_f32_16x16x32_bf16(AV[i_], BV[j_], acc[i_][j_], 0, 0, 0); \
        __builtin_amdgcn_s_setprio(0);                                        \
    } while (0)

    bf16x8 avX[8], bvX[4], avY[8], bvY[4];

    // prologue: stage K-tiles 0..2 (12 loads); wait tiles 0,1 (vmcnt(4) leaves S2); barrier
    STAGE(0, 0); STAGE(1, 32); STAGE(2, 64);
    asm volatile("s_waitcnt vmcnt(4)" ::: "memory");
    SBAR();
    RD_FRAGS(avX, bvX, 0);

    for (int t = 0; t < NT; t += 2) {
        // ---- even iter t: MFMA on X, prefetch frags(t+1) into Y ----
        if (t + 1 < NT) RD_FRAGS(avY, bvY, t + 1);
        if (t + 3 < NT) STAGE((t + 3) & 3, (t + 3) * 32);
        MFMA_ALL(avX, bvX);
        if (t + 3 < NT)      asm volatile("s_waitcnt vmcnt(4)" ::: "memory");
        else if (t + 2 < NT) asm volatile("s_waitcnt vmcnt(0)" ::: "memory");
        SBAR();
        // ---- odd iter t+1: MFMA on Y, prefetch frags(t+2) into X ----
        if (t + 2 < NT) RD_FRAGS(avX, bvX, t + 2);
        if (t + 4 < NT) STAGE((t + 4) & 3, (t + 4) * 32);
        MFMA_ALL(avY, bvY);
        if (t + 4 < NT)      asm volatile("s_waitcnt vmcnt(4)" ::: "memory");
        else if (t + 3 < NT) asm volatile("s_waitcnt vmcnt(0)" ::: "memory");
        SBAR();
    }
#undef RD_FRAGS
#undef MFMA_ALL

    size_t pbase = (size_t)bzi * ((size_t)M * N);
#pragma unroll
    for (int i = 0; i < 8; ++i)
#pragma unroll
        for (int r = 0; r < 4; ++r) {
            int row = bm + wm + i * 16 + q * 4 + r;
#pragma unroll
            for (int j = 0; j < 4; ++j) {
                int col = bn + wn + j * 16 + ln16;
                size_t idx = (size_t)row * N + col;
                float v = acc[i][j][r];
                if (EPI == 0) Cb[idx] = __float2bfloat16(v);
                else          Pb[pbase + idx] = __float2bfloat16(v);
            }
        }
}

// ---------------- split-K reduce kernels (bf16 partials) ----------------
__global__ __launch_bounds__(256) void reduce_plain(const bf16* __restrict__ P, int ns, size_t MN,
                                                    bf16* __restrict__ O) {
    size_t i = ((size_t)blockIdx.x * 256 + threadIdx.x) * 4;
    float s[4] = {0.f, 0.f, 0.f, 0.f};
    for (int k = 0; k < ns; ++k) {
        ushort4 p = *reinterpret_cast<const ushort4*>(&P[(size_t)k * MN + i]);
        s[0] += bits2f(p.x); s[1] += bits2f(p.y); s[2] += bits2f(p.z); s[3] += bits2f(p.w);
    }
    bf16 r[4];
#pragma unroll
    for (int j = 0; j < 4; ++j) r[j] = __float2bfloat16(s[j]);
    *reinterpret_cast<ushort4*>(&O[i]) = *reinterpret_cast<ushort4*>(r);
}

__global__ __launch_bounds__(256) void reduce_gate(const bf16* __restrict__ P, int ns, size_t MN,
                                                   const bf16* __restrict__ XZ, bf16* __restrict__ YM) {
    size_t i = ((size_t)blockIdx.x * 256 + threadIdx.x) * 4;  // over T_TOK*DI
    float s[4] = {0.f, 0.f, 0.f, 0.f};
    for (int k = 0; k < ns; ++k) {
        ushort4 p = *reinterpret_cast<const ushort4*>(&P[(size_t)k * MN + i]);
        s[0] += bits2f(p.x); s[1] += bits2f(p.y); s[2] += bits2f(p.z); s[3] += bits2f(p.w);
    }
    int t = (int)(i >> 11), c = (int)(i & (DI - 1));
    const bf16* zp = &XZ[(size_t)t * N2 + DI + c];
    bf16 r[4];
#pragma unroll
    for (int j = 0; j < 4; ++j) {
        float z = b2f(zp[j]);
        r[j] = __float2bfloat16(s[j] * (z / (1.f + __expf(-z))));
    }
    *reinterpret_cast<ushort4*>(&YM[i]) = *reinterpret_cast<ushort4*>(r);
}

__global__ __launch_bounds__(256) void reduce_out(const bf16* __restrict__ P, int ns, size_t MN,
                                                  const float* __restrict__ x, float* __restrict__ out) {
    size_t i = ((size_t)blockIdx.x * 256 + threadIdx.x) * 4;  // over T_TOK*DM
    float s[4] = {0.f, 0.f, 0.f, 0.f};
    for (int k = 0; k < ns; ++k) {
        ushort4 p = *reinterpret_cast<const ushort4*>(&P[(size_t)k * MN + i]);
        s[0] += bits2f(p.x); s[1] += bits2f(p.y); s[2] += bits2f(p.z); s[3] += bits2f(p.w);
    }
    float4 xv = *reinterpret_cast<const float4*>(&x[i]);
    float4 o = {s[0] + xv.x, s[1] + xv.y, s[2] + xv.z, s[3] + xv.w};
    *reinterpret_cast<float4*>(&out[i]) = o;
}

__global__ __launch_bounds__(256) void reduce_xdbl(const bf16* __restrict__ P, int ns, size_t MN,
                                                   float* __restrict__ XDP, bf16* __restrict__ XDdt) {
    size_t i = ((size_t)blockIdx.x * 256 + threadIdx.x) * 4;  // over 2*T_TOK*128
    float s[4] = {0.f, 0.f, 0.f, 0.f};
    for (int k = 0; k < ns; ++k) {
        ushort4 p = *reinterpret_cast<const ushort4*>(&P[(size_t)k * MN + i]);
        s[0] += bits2f(p.x); s[1] += bits2f(p.y); s[2] += bits2f(p.z); s[3] += bits2f(p.w);
    }
    float4 o = {s[0], s[1], s[2], s[3]};
    *reinterpret_cast<float4*>(&XDP[i]) = o;
    int col = (int)(i & (XDP_LD - 1));
    if (col < DTR) {
        size_t row = i >> 7;
        bf16 r[4];
#pragma unroll
        for (int j = 0; j < 4; ++j) r[j] = __float2bfloat16(s[j]);
        *reinterpret_cast<ushort4*>(&XDdt[row * DTR + col]) = *reinterpret_cast<ushort4*>(r);
    }
}

// ---------------- dt GEMM fallback (vector, K=64, reads XDP fp32) ----------------
__global__ __launch_bounds__(256) void gemm_dt(const float* __restrict__ A,   // lda=128
                                               const float* __restrict__ Bw,  // 64 x 2048 f32
                                               const float* __restrict__ bias,
                                               bf16* __restrict__ Cb, int M, int N) {
    __shared__ float As[16][68];
    __shared__ float Bs[16][68];
    int tid = threadIdx.x;
    int bm = blockIdx.y * 64, bn = blockIdx.x * 64;
    int tx = tid & 15, ty = tid >> 4;
    float acc[4][4];
#pragma unroll
    for (int i = 0; i < 4; ++i)
#pragma unroll
        for (int j = 0; j < 4; ++j) acc[i][j] = 0.f;
    int arow = tid >> 2, acg = (tid & 3) * 4;
    int brow = tid >> 4, bcol = (tid & 15) * 4;
    for (int k0 = 0; k0 < DTR; k0 += 16) {
        float4 av = *reinterpret_cast<const float4*>(&A[(size_t)(bm + arow) * XDP_LD + k0 + acg]);
        As[acg + 0][arow] = av.x; As[acg + 1][arow] = av.y;
        As[acg + 2][arow] = av.z; As[acg + 3][arow] = av.w;
        float4 bv = *reinterpret_cast<const float4*>(&Bw[(size_t)(k0 + brow) * N + bn + bcol]);
        Bs[brow][bcol + 0] = bv.x; Bs[brow][bcol + 1] = bv.y;
        Bs[brow][bcol + 2] = bv.z; Bs[brow][bcol + 3] = bv.w;
        __syncthreads();
#pragma unroll
        for (int kk = 0; kk < 16; ++kk) {
            float4 a = *reinterpret_cast<const float4*>(&As[kk][ty * 4]);
            float4 b = *reinterpret_cast<const float4*>(&Bs[kk][tx * 4]);
            acc[0][0] += a.x * b.x; acc[0][1] += a.x * b.y; acc[0][2] += a.x * b.z; acc[0][3] += a.x * b.w;
            acc[1][0] += a.y * b.x; acc[1][1] += a.y * b.y; acc[1][2] += a.y * b.z; acc[1][3] += a.y * b.w;
            acc[2][0] += a.z * b.x; acc[2][1] += a.z * b.y; acc[2][2] += a.z * b.z; acc[2][3] += a.z * b.w;
            acc[3][0] += a.w * b.x; acc[3][1] += a.w * b.y; acc[3][2] += a.w * b.z; acc[3][3] += a.w * b.w;
        }
        __syncthreads();
    }
    int row0 = bm + ty * 4, col0 = bn + tx * 4;
#pragma unroll
    for (int i = 0; i < 4; ++i)
#pragma unroll
        for (int j = 0; j < 4; ++j) {
            float v = acc[i][j] + bias[col0 + j];
            Cb[(size_t)(row0 + i) * N + col0 + j] = __float2bfloat16(softplus_fast(v));
        }
}

// ---------------- depthwise causal conv (fwd) + anti-causal (bwd) + SiLU ----------------
// Vectorized (G13): 1 thread = 8 consecutive channels; taps are bf16x8 16B loads,
// weights contiguous float4s, outputs bf16x8. Block covers one token x all channels
// -> each XZ row access is a contiguous coalesced 4KB sweep (tap overlap hits L2).
__global__ __launch_bounds__(256) void conv_kernel(const bf16* __restrict__ XZ,
                                                   const float* __restrict__ wf, const float* __restrict__ bf_,
                                                   const float* __restrict__ wb, const float* __restrict__ bb_,
                                                   bf16* __restrict__ XCF, bf16* __restrict__ XCB) {
    int idx = blockIdx.x * 256 + threadIdx.x;   // over T_TOK*DI/8
    int cg = idx & (DI / 8 - 1);
    int c0 = cg * 8;
    int g = idx >> 8;                 // token index
    int l = g & (SEQ - 1);
    int b = g >> 10;
    float sf[8], sb[8];
    float4 wfv[8], wbv[8];
#pragma unroll
    for (int u = 0; u < 8; ++u) {
        wfv[u] = *(const float4*)&wf[(c0 + u) * 4];
        wbv[u] = *(const float4*)&wb[(c0 + u) * 4];
        sf[u] = bf_[c0 + u];
        sb[u] = bb_[c0 + u];
    }
#pragma unroll
    for (int j = 0; j < 4; ++j) {
        int lf = l - 3 + j;
        if (lf >= 0) {
            bf16x8 v = *(const bf16x8*)&XZ[((size_t)(b * SEQ + lf)) * N2 + c0];
#pragma unroll
            for (int u = 0; u < 8; ++u) {
                float w = (j == 0) ? wfv[u].x : (j == 1) ? wfv[u].y : (j == 2) ? wfv[u].z : wfv[u].w;
                sf[u] += w * bits2f((unsigned short)v[u]);
            }
        }
        int lb = l + 3 - j;
        if (lb < SEQ) {
            bf16x8 v = *(const bf16x8*)&XZ[((size_t)(b * SEQ + lb)) * N2 + c0];
#pragma unroll
            for (int u = 0; u < 8; ++u) {
                float w = (j == 0) ? wbv[u].x : (j == 1) ? wbv[u].y : (j == 2) ? wbv[u].z : wbv[u].w;
                sb[u] += w * bits2f((unsigned short)v[u]);
            }
        }
    }
    bf16 rf[8], rb[8];
#pragma unroll
    for (int u = 0; u < 8; ++u) {
        rf[u] = __float2bfloat16(sf[u] / (1.f + __expf(-sf[u])));
        rb[u] = __float2bfloat16(sb[u] / (1.f + __expf(-sb[u])));
    }
    size_t o = (size_t)g * DI + c0;
    *(bf16x8*)&XCF[o] = *(bf16x8*)rf;
    *(bf16x8*)&XCB[o] = *(bf16x8*)rb;
}

// ---------------- chunked selective scan (3 kernels, HW stream barriers) ----------------
// NC=32 (CLEN=32), best measured (R8). 2 threads per channel (8 states each); DT/XC
// tiles bulk-staged into LDS via bf16x8 coalesced loads. R9's NC=64 test regressed
// (doubled HLOC traffic + halved staging efficiency; confounded by pod variance).
template <int NC, bool FINAL>
__global__ __launch_bounds__(256) void scan_chunk(const bf16* __restrict__ DTF_, const bf16* __restrict__ DTB_,
                                                  const bf16* __restrict__ XCF_, const bf16* __restrict__ XCB_,
                                                  const float* __restrict__ XDP,
                                                  const float* __restrict__ Af, const float* __restrict__ Ab,
                                                  const float* __restrict__ Df, const float* __restrict__ Db,
                                                  float* __restrict__ HLOC, float* __restrict__ SUMDT,
                                                  bf16* __restrict__ YCAT) {
    constexpr int CL = SEQ / NC;
    __shared__ float bsl[CL][32];
    __shared__ bf16 dtl[CL][128];
    __shared__ bf16 xcl[CL][128];
    int tid = threadIdx.x;
    int sg = tid & 1;                          // state group: states sg*8 .. sg*8+7
    int cl = tid >> 1;                         // channel local 0..127
    int cbase = blockIdx.x * 128;
    int c = cbase + cl;
    int b = blockIdx.y;
    int dir = (int)blockIdx.z >= NC;
    int chunk = blockIdx.z - dir * NC;
    const bf16* DT = dir ? DTB_ : DTF_;
    const bf16* XC = dir ? XCB_ : XCF_;
    // stage B/C rows for the whole chunk: CL tokens x 32 floats
    for (int i = tid; i < CL * 8; i += 256) {
        int it = i >> 3, j4 = (i & 7) * 4;
        int sit = chunk * CL + it;
        int l = dir ? (SEQ - 1 - sit) : sit;
        size_t row = (size_t)dir * T_TOK + (size_t)b * SEQ + l;
        *(float4*)&bsl[it][j4] = *(const float4*)&XDP[row * XDP_LD + DTR + j4];
    }
    // stage DT/XC tiles: CL tokens x 128 channels, 16B chunks, fully coalesced
    for (int ch = tid; ch < CL * 16; ch += 256) {
        int it = ch >> 4, of = (ch & 15) * 8;
        int sit = chunk * CL + it;
        int l = dir ? (SEQ - 1 - sit) : sit;
        size_t g = (size_t)b * SEQ + l;
        *(bf16x8*)&dtl[it][of] = *(const bf16x8*)&DT[g * DI + cbase + of];
        *(bf16x8*)&xcl[it][of] = *(const bf16x8*)&XC[g * DI + cbase + of];
    }
    const float* Al = dir ? Ab : Af;
    float A[8];
#pragma unroll
    for (int n = 0; n < 8; ++n) A[n] = -__expf(Al[c * NST + sg * 8 + n]);
    size_t base = ((((size_t)dir * BATCH + b) * NC + chunk) * DI + c);
    float h[8];
    float Dv = 0.f;
    if (FINAL) {
#pragma unroll
        for (int n = 0; n < 8; ++n) h[n] = HLOC[base * NST + sg * 8 + n];
        Dv = (dir ? Db : Df)[c];
    } else {
#pragma unroll
        for (int n = 0; n < 8; ++n) h[n] = 0.f;
    }
    __syncthreads();
    float sumdt = 0.f;
    for (int it = 0; it < CL; ++it) {
        int sit = chunk * CL + it;
        int l = dir ? (SEQ - 1 - sit) : sit;
        size_t g = (size_t)b * SEQ + l;
        float dt = b2f(dtl[it][cl]);
        float xc = b2f(xcl[it][cl]);
        float dtxc = dt * xc;
        const float* bs = &bsl[it][sg * 8];
        if (FINAL) {
            float y = 0.f;
#pragma unroll
            for (int n = 0; n < 8; ++n) {
                h[n] = __expf(dt * A[n]) * h[n] + dtxc * bs[n];
                y += h[n] * bs[NST + n];
            }
            y += __shfl_xor(y, 1);
            if (!sg) YCAT[g * N2 + dir * DI + c] = __float2bfloat16(y + xc * Dv);
        } else {
            sumdt += dt;
#pragma unroll
            for (int n = 0; n < 8; ++n)
                h[n] = __expf(dt * A[n]) * h[n] + dtxc * bs[n];
        }
    }
    if (!FINAL) {
#pragma unroll
        for (int n = 0; n < 8; ++n) HLOC[base * NST + sg * 8 + n] = h[n];
        if (!sg) SUMDT[base] = sumdt;
    }
}

// phase B: sequential combine over chunks; rewrites HLOC[k] with carry-in h for chunk k
__global__ __launch_bounds__(256) void scan_combine(float* __restrict__ HLOC,
                                                    const float* __restrict__ SUMDT,
                                                    const float* __restrict__ Af,
                                                    const float* __restrict__ Ab, int nchunk) {
    int idx = blockIdx.x * 256 + threadIdx.x;   // over 2*BATCH*DI*NST = 131072
    int n = idx & 15;
    int c = (idx >> 4) & (DI - 1);
    int b = (idx >> 15) & 1;
    int dir = idx >> 16;
    float A = -__expf((dir ? Ab : Af)[c * NST + n]);
    float h = 0.f;
    for (int k = 0; k < nchunk; ++k) {
        size_t base = ((((size_t)dir * BATCH + b) * nchunk + k) * DI + c);
        float P = __expf(A * SUMDT[base]);
        float hl = HLOC[base * NST + n];
        HLOC[base * NST + n] = h;
        h = P * h + hl;
    }
}

// ---------------- gating fallback: YM *= silu(z) ----------------
__global__ __launch_bounds__(256) void gate_kernel(bf16* __restrict__ YM, const bf16* __restrict__ XZ) {
    int idx = blockIdx.x * 256 + threadIdx.x;  // over T_TOK*DI
    int t = idx >> 11;
    int c = idx & (DI - 1);
    float z = b2f(XZ[(size_t)t * N2 + DI + c]);
    float y = b2f(YM[idx]);
    YM[idx] = __float2bfloat16(y * (z / (1.f + __expf(-z))));
}

extern "C" void kernel_launch(void* const* d_in, const int* in_sizes, int n_in,
                              void* d_out, int out_size, void* d_ws, size_t ws_size,
                              hipStream_t stream) {
    const float* x       = (const float*)d_in[0];
    const float* gamma   = (const float*)d_in[1];
    const float* beta    = (const float*)d_in[2];
    const float* in_w    = (const float*)d_in[3];
    const float* conv_w  = (const float*)d_in[4];
    const float* conv_b  = (const float*)d_in[5];
    const float* xproj_w = (const float*)d_in[6];
    const float* dt_w    = (const float*)d_in[7];
    const float* dt_b    = (const float*)d_in[8];
    const float* A_log   = (const float*)d_in[9];
    const float* D_skip  = (const float*)d_in[10];
    const float* conv_w_b  = (const float*)d_in[11];
    const float* conv_b_b  = (const float*)d_in[12];
    const float* xproj_w_b = (const float*)d_in[13];
    const float* dt_w_b    = (const float*)d_in[14];
    const float* dt_b_b    = (const float*)d_in[15];
    const float* A_log_b   = (const float*)d_in[16];
    const float* D_skip_b  = (const float*)d_in[17];
    const float* merge_w   = (const float*)d_in[18];
    const float* out_w     = (const float*)d_in[19];
    float* out = (float*)d_out;

    // ---- base workspace layout ----
    char* w = (char*)d_ws;
    size_t off = 0;
    bf16* H       = (bf16*)(w + off); off += (size_t)T_TOK * DM * 2;          //  4.19 MB
    bf16* XZ      = (bf16*)(w + off); off += (size_t)T_TOK * N2 * 2;          // 16.78 MB
    bf16* XCF     = (bf16*)(w + off); off += (size_t)T_TOK * DI * 2;          //  8.39 MB
    bf16* XCB     = (bf16*)(w + off); off += (size_t)T_TOK * DI * 2;          //  8.39 MB
    bf16* XPF     = (bf16*)(w + off); off += (size_t)XDP_LD * DI * 2;         //  0.52 MB
    bf16* XPB     = (bf16*)(w + off); off += (size_t)XDP_LD * DI * 2;         //  0.52 MB
    float* XDP    = (float*)(w + off); off += (size_t)2 * T_TOK * XDP_LD * 4; //  2.10 MB
    bf16* DTF     = (bf16*)(w + off); off += (size_t)T_TOK * DI * 2;          //  8.39 MB
    bf16* DTB     = (bf16*)(w + off); off += (size_t)T_TOK * DI * 2;          //  8.39 MB (contig after DTF)
    bf16* YCAT    = (bf16*)(w + off); off += (size_t)T_TOK * N2 * 2;          // 16.78 MB
    bf16* in_wT   = (bf16*)(w + off); off += (size_t)N2 * DM * 2;             //  8.39 MB
    bf16* out_wT  = (bf16*)(w + off); off += (size_t)DM * DI * 2;             //  4.19 MB
    bf16* merge_wT= (bf16*)(w + off); off += (size_t)DI * N2 * 2;             // 16.78 MB
    bf16* dtwT    = (bf16*)(w + off); off += (size_t)2 * DI * DTR * 2;        //  0.52 MB
    bf16* XDdt    = (bf16*)(w + off); off += (size_t)2 * T_TOK * DTR * 2;     //  0.52 MB
    // PART region: time-shared {xz partials | xdbl partials | HLOC+SUMDT | merge partials | out partials}
    char* PART = w + off;
    size_t avail = (ws_size > off) ? ws_size - off : 0;

    float* HLOC  = (float*)PART;                                              // 8.39 MB (NCHUNK=32)
    float* SUMDT = (float*)(PART + (size_t)2 * BATCH * NCHUNK * DI * NST * 4);// +0.52 MB
    bf16* Pb     = (bf16*)PART;                                               // split-K bf16 partials
    bf16* YM     = DTF;    // alias: DTF dead after scan C

    size_t MNm = (size_t)T_TOK * DI;          // merge partial elems
    size_t MNo = (size_t)T_TOK * DM;          // out partial elems
    size_t MNx = (size_t)2 * T_TOK * XDP_LD;  // xdbl partial elems
    size_t MNz = (size_t)T_TOK * N2;          // xz partial elems
    int s_merge = (avail >= 4 * MNm * 2) ? 4 : (avail >= 2 * MNm * 2) ? 2 : 0;
    int s_out   = (avail >= 4 * MNo * 2) ? 4 : (avail >= 2 * MNo * 2) ? 2 : 0;
    int s_xdbl  = (avail >= 16 * MNx * 2) ? 16 : (avail >= 8 * MNx * 2) ? 8 : (avail >= 4 * MNx * 2) ? 4 : 0;
    int s_xz    = (avail >= 2 * MNz * 2) ? 2 : 0;

    // 1. mega prep: LN + in_wT + out_wT + merge_wT + xproj/dtw
    prep_mega<<<LN_BLKS + INW_T + OUTW_T + MRGW_T + SMALL_BLK, 256, 0, stream>>>(
        x, gamma, beta, H, in_w, in_wT, out_w, out_wT, merge_w, merge_wT,
        xproj_w, xproj_w_b, XPF, XPB, dt_w, dt_w_b, dtwT);
    // 2. xz = H @ in_w  (M=2048, N=4096, K=1024) -> XZ bf16
    if (s_xz) {
        gemm256<3><<<dim3(N2 / 256, T_TOK / 256, s_xz), 512, 0, stream>>>(
            H, in_wT, nullptr, Pb, T_TOK, N2, DM);
        reduce_plain<<<(int)(MNz / 4 / 256), 256, 0, stream>>>(Pb, s_xz, MNz, XZ);
    } else {
        mfma_gemm<0><<<dim3(N2 / 128, T_TOK / 128), 256, 0, stream>>>(
            H, in_wT, in_wT, 1 << 30, XZ, nullptr, nullptr, nullptr, nullptr, nullptr, T_TOK, N2, DM);
    }
    // 3. depthwise conv + silu, both dirs (vectorized: 8 channels/thread)
    conv_kernel<<<(T_TOK * DI / 8) / 256, 256, 0, stream>>>(XZ, conv_w, conv_b, conv_w_b, conv_b_b, XCF, XCB);
    // 4. x_dbl (padded): XDP = [XCF;XCB] @ xproj (M=4096, N=128, K=2048), B per dir
    if (s_xdbl) {
        mfma_gemm<3><<<dim3(1, (2 * T_TOK) / 128, s_xdbl), 256, 0, stream>>>(
            XCF, XPF, XPB, (T_TOK / 128), nullptr, nullptr, nullptr, Pb, nullptr, nullptr,
            2 * T_TOK, XDP_LD, DI);
        reduce_xdbl<<<(int)(MNx / 4 / 256), 256, 0, stream>>>(Pb, s_xdbl, MNx, XDP, XDdt);
        // 5. dt = softplus(XDdt @ dt_w + dt_b) via MFMA (M=4096 both dirs, N=2048, K=64)
        mfma_gemm<4><<<dim3(DI / 128, (2 * T_TOK) / 128), 256, 0, stream>>>(
            XDdt, dtwT, dtwT + (size_t)DI * DTR, (T_TOK / 128), DTF, nullptr, nullptr, nullptr,
            dt_b, dt_b_b, 2 * T_TOK, DI, DTR);
    } else {
        mfma_gemm<2><<<dim3(1, (2 * T_TOK) / 128), 256, 0, stream>>>(
            XCF, XPF, XPB, (T_TOK / 128), nullptr, nullptr, XDP, nullptr, nullptr, nullptr,
            2 * T_TOK, XDP_LD, DI);
        gemm_dt<<<dim3(DI / 64, T_TOK / 64), 256, 0, stream>>>(XDP, dt_w, dt_b, DTF, T_TOK, DI);
        gemm_dt<<<dim3(DI / 64, T_TOK / 64), 256, 0, stream>>>(XDP + (size_t)T_TOK * XDP_LD, dt_w_b, dt_b_b, DTB, T_TOK, DI);
    }
    // 6-8. chunked scan (3 kernels; stream boundaries are the grid barriers)
    scan_chunk<NCHUNK, false><<<dim3(DI / 128, BATCH, 2 * NCHUNK), 256, 0, stream>>>(
        DTF, DTB, XCF, XCB, XDP, A_log, A_log_b, D_skip, D_skip_b, HLOC, SUMDT, YCAT);
    scan_combine<<<(2 * BATCH * DI * NST) / 256, 256, 0, stream>>>(HLOC, SUMDT, A_log, A_log_b, NCHUNK);
    scan_chunk<NCHUNK, true><<<dim3(DI / 128, BATCH, 2 * NCHUNK), 256, 0, stream>>>(
        DTF, DTB, XCF, XCB, XDP, A_log, A_log_b, D_skip, D_skip_b, HLOC, SUMDT, YCAT);
    // 9. YM = silu(z) * (YCAT @ merge_w) (M=2048, N=2048, K=4096)
    if (s_merge) {
        gemm256<3><<<dim3(DI / 256, T_TOK / 256, s_merge), 512, 0, stream>>>(
            YCAT, merge_wT, nullptr, Pb, T_TOK, DI, N2);
        reduce_gate<<<(int)(MNm / 4 / 256), 256, 0, stream>>>(Pb, s_merge, MNm, XZ, YM);
    } else {
        mfma_gemm<0><<<dim3(DI / 128, T_TOK / 128), 256, 0, stream>>>(
            YCAT, merge_wT, merge_wT, 1 << 30, YM, nullptr, nullptr, nullptr, nullptr, nullptr,
            T_TOK, DI, N2);
        gate_kernel<<<(T_TOK * DI) / 256, 256, 0, stream>>>(YM, XZ);
    }
    // 10. out = x + YM @ out_w (M=2048, N=1024, K=2048), f32
    if (s_out) {
        mfma_gemm<3><<<dim3(DM / 128, T_TOK / 128, s_out), 256, 0, stream>>>(
            YM, out_wT, out_wT, 1 << 30, nullptr, nullptr, nullptr, Pb, nullptr, nullptr,
            T_TOK, DM, DI);
        reduce_out<<<(int)(MNo / 4 / 256), 256, 0, stream>>>(Pb, s_out, MNo, x, out);
    } else {
        mfma_gemm<1><<<dim3(DM / 128, T_TOK / 128), 256, 0, stream>>>(
            YM, out_wT, out_wT, 1 << 30, nullptr, x, out, nullptr, nullptr, nullptr,
            T_TOK, DM, DI);
    }
}

// Round 11
// 388.040 us; speedup vs baseline: 1.0527x; 1.0264x over previous
//
#include <hip/hip_runtime.h>
#include <hip/hip_bf16.h>
#include <math.h>

typedef __hip_bfloat16 bf16;
typedef unsigned int u32;
typedef __attribute__((ext_vector_type(8))) short bf16x8;
typedef __attribute__((ext_vector_type(4))) float f32x4;

#define BATCH 2
#define SEQ 1024
#define DM 1024
#define DI 2048
#define NST 16
#define DTR 64
#define XDN 96          // dt_rank + 2*N = 64+32
#define XDP_LD 128      // padded x_dbl row
#define T_TOK 2048      // BATCH*SEQ
#define N2 4096         // 2*DI
#define NCHUNK 32
#define CLEN 32

static __device__ __forceinline__ float b2f(bf16 v) { return __bfloat162float(v); }
static __device__ __forceinline__ float bits2f(unsigned short u) {
    return __uint_as_float(((unsigned)u) << 16);
}

// fast softplus: 2 HW transcendentals instead of libm log1pf (branchy, ~5x VALU)
static __device__ __forceinline__ float softplus_fast(float t) {
    return (t > 20.f) ? t : __logf(1.f + __expf(t));
}

// ---- async global->LDS, 16 bytes per lane; LDS dest must be wave-uniform base ----
static __device__ __forceinline__ void gload_lds16(const void* g, void* l) {
    __builtin_amdgcn_global_load_lds((__attribute__((address_space(1))) u32*)(size_t)g,
                                     (__attribute__((address_space(3))) u32*)l, 16, 0, 0);
}

// compiler memory fence + raw barrier (no vmcnt drain, unlike __syncthreads)
#define SBAR() do { asm volatile("" ::: "memory"); __builtin_amdgcn_s_barrier(); asm volatile("" ::: "memory"); } while (0)

// ---- 32x32 LDS tile transpose helper: in f32 [K][N] -> out bf16 [N][K] ----
static __device__ void tileT(const float* __restrict__ in, bf16* __restrict__ out,
                             int K, int N, int t, float (*tb)[33]) {
    int nt = N >> 5;
    int bx = (t % nt) << 5, by = (t / nt) << 5;
    int tx = threadIdx.x & 31, r0 = threadIdx.x >> 5;
#pragma unroll
    for (int r = r0; r < 32; r += 8)
        tb[r][tx] = in[(size_t)(by + r) * N + bx + tx];
    __syncthreads();
#pragma unroll
    for (int r = r0; r < 32; r += 8)
        out[(size_t)(bx + r) * K + by + tx] = __float2bfloat16(tb[tx][r]);
}

#define LN_BLKS   T_TOK                       // 2048
#define INW_T     ((N2 / 32) * (DM / 32))     // 4096
#define OUTW_T    ((DM / 32) * (DI / 32))     // 2048
#define MRGW_T    ((DI / 32) * (N2 / 32))     // 8192
#define SMALL_BLK ((2 * XDP_LD * DI + 2 * DI * DTR) / 256)  // 3072

// ---------------- prep_mega: LN + all weight preps ----------------
__global__ __launch_bounds__(256) void prep_mega(const float* __restrict__ x,
                                                 const float* __restrict__ gamma,
                                                 const float* __restrict__ beta,
                                                 bf16* __restrict__ H,
                                                 const float* __restrict__ in_w, bf16* __restrict__ in_wT,
                                                 const float* __restrict__ out_w, bf16* __restrict__ out_wT,
                                                 const float* __restrict__ merge_w, bf16* __restrict__ merge_wT,
                                                 const float* __restrict__ xpf, const float* __restrict__ xpb,
                                                 bf16* __restrict__ XPF, bf16* __restrict__ XPB,
                                                 const float* __restrict__ dtwf, const float* __restrict__ dtwb,
                                                 bf16* __restrict__ dtwT) {
    __shared__ float tbuf[32][33];
    __shared__ float red[8];
    int bid = blockIdx.x;
    int tid = threadIdx.x;

    if (bid < LN_BLKS) {
        // ---- LayerNorm, one token per block ----
        int t = bid;
        float xv[4];
        float s = 0.f, s2 = 0.f;
#pragma unroll
        for (int k = 0; k < 4; ++k) {
            float v = x[(size_t)t * DM + k * 256 + tid];
            xv[k] = v; s += v; s2 += v * v;
        }
#pragma unroll
        for (int off = 32; off; off >>= 1) {
            s  += __shfl_down(s, off);
            s2 += __shfl_down(s2, off);
        }
        int wid = tid >> 6, lane = tid & 63;
        if (!lane) { red[wid] = s; red[4 + wid] = s2; }
        __syncthreads();
        if (tid == 0) {
            float S = red[0] + red[1] + red[2] + red[3];
            float S2 = red[4] + red[5] + red[6] + red[7];
            float mu = S * (1.f / DM);
            float var = S2 * (1.f / DM) - mu * mu;
            red[0] = mu;
            red[1] = rsqrtf(var + 1e-5f);
        }
        __syncthreads();
        float mu = red[0], rs = red[1];
#pragma unroll
        for (int k = 0; k < 4; ++k) {
            int i = k * 256 + tid;
            H[(size_t)t * DM + i] = __float2bfloat16((xv[k] - mu) * rs * gamma[i] + beta[i]);
        }
        return;
    }
    bid -= LN_BLKS;
    if (bid < INW_T)  { tileT(in_w, in_wT, DM, N2, bid, tbuf); return; }
    bid -= INW_T;
    if (bid < OUTW_T) { tileT(out_w, out_wT, DI, DM, bid, tbuf); return; }
    bid -= OUTW_T;
    if (bid < MRGW_T) { tileT(merge_w, merge_wT, N2, DI, bid, tbuf); return; }
    bid -= MRGW_T;
    // small: xproj pad-transpose + dt_w transpose
    int idx = bid * 256 + tid;
    if (idx < 2 * XDP_LD * DI) {
        int dir = idx >= XDP_LD * DI;
        int i = idx - dir * (XDP_LD * DI);
        int n = i >> 11;
        int k = i & (DI - 1);
        float v = (n < XDN) ? (dir ? xpb : xpf)[k * XDN + n] : 0.f;
        (dir ? XPB : XPF)[i] = __float2bfloat16(v);
    } else {
        int j = idx - 2 * XDP_LD * DI;     // over 2*2048*64
        int dir = j >= DI * DTR;
        int e = j - dir * (DI * DTR);
        int n = e >> 6;
        int k = e & 63;
        dtwT[(size_t)dir * DI * DTR + n * DTR + k] =
            __float2bfloat16((dir ? dtwb : dtwf)[(size_t)k * DI + n]);
    }
}

// ---------------- MFMA GEMM: C(MxN) = A(MxK,bf16,row-major) * BT(NxK,bf16)^T ----------------
// 128x128 tile, BK=64, 4 waves each 64x64 (4x4 of 16x16x32 MFMA); split-K over gridDim.z
template <int EPI>
__global__ __launch_bounds__(256) void mfma_gemm(const bf16* __restrict__ A,
                                                 const bf16* __restrict__ BT,
                                                 const bf16* __restrict__ BT2, int bysplit,
                                                 bf16* __restrict__ Cb,
                                                 const float* __restrict__ resid,
                                                 float* __restrict__ outf,
                                                 bf16* __restrict__ Pb,
                                                 const float* __restrict__ bias1,
                                                 const float* __restrict__ bias2,
                                                 int M, int N, int K) {
    __shared__ bf16 As[8192];   // [kg 0..7][m 0..127][8]
    __shared__ bf16 Bs[8192];   // [kg 0..7][n 0..127][8]
    int tid = threadIdx.x;
    int wave = tid >> 6, lane = tid & 63;
    int q = lane >> 4, ln16 = lane & 15;
    int bm = blockIdx.y * 128, bn = blockIdx.x * 128;
    int wm = (wave >> 1) * 64, wn = (wave & 1) * 64;
    const bf16* Bt = ((int)blockIdx.y < bysplit) ? BT : BT2;

    int ks = K / gridDim.z;
    int kb = blockIdx.z * ks;

    f32x4 zf; zf[0] = zf[1] = zf[2] = zf[3] = 0.f;
    f32x4 acc[4][4];
#pragma unroll
    for (int i = 0; i < 4; ++i)
#pragma unroll
        for (int j = 0; j < 4; ++j) acc[i][j] = zf;

    for (int k0 = kb; k0 < kb + ks; k0 += 64) {
#pragma unroll
        for (int i = 0; i < 4; ++i) {
            int s = wave * 256 + i * 64 + lane;   // slot 0..1023
            int kg = s >> 7, m = s & 127;
            gload_lds16(&A[(size_t)(bm + m) * K + k0 + kg * 8], &As[(wave * 256 + i * 64) * 8]);
            gload_lds16(&Bt[(size_t)(bn + m) * K + k0 + kg * 8], &Bs[(wave * 256 + i * 64) * 8]);
        }
        __syncthreads();
#pragma unroll
        for (int kk = 0; kk < 2; ++kk) {
            bf16x8 af[4], bfr[4];
#pragma unroll
            for (int i = 0; i < 4; ++i) {
                af[i]  = *(const bf16x8*)&As[(((kk * 4 + q) * 128) + (wm + i * 16 + ln16)) * 8];
                bfr[i] = *(const bf16x8*)&Bs[(((kk * 4 + q) * 128) + (wn + i * 16 + ln16)) * 8];
            }
#pragma unroll
            for (int i = 0; i < 4; ++i)
#pragma unroll
                for (int j = 0; j < 4; ++j)
                    acc[i][j] = __builtin_amdgcn_mfma_f32_16x16x32_bf16(af[i], bfr[j], acc[i][j], 0, 0, 0);
        }
        __syncthreads();
    }

    size_t pbase = (size_t)blockIdx.z * M * N;
#pragma unroll
    for (int i = 0; i < 4; ++i)
#pragma unroll
        for (int r = 0; r < 4; ++r) {
            int row = bm + wm + i * 16 + q * 4 + r;
            const float* bias = (EPI == 4) ? ((row < T_TOK) ? bias1 : bias2) : nullptr;
#pragma unroll
            for (int j = 0; j < 4; ++j) {
                int col = bn + wn + j * 16 + ln16;
                size_t idx = (size_t)row * N + col;
                float v = acc[i][j][r];
                if (EPI == 0)      Cb[idx] = __float2bfloat16(v);
                else if (EPI == 1) outf[idx] = resid[idx] + v;
                else if (EPI == 2) outf[idx] = v;
                else if (EPI == 3) Pb[pbase + idx] = __float2bfloat16(v);
                else {
                    Cb[idx] = __float2bfloat16(softplus_fast(v + bias[col]));
                }
            }
        }
}

// ---------------- gemm256: 256x256 tile, 8 waves, BK=32, quad-buffered LDS ----------------
// R3 register-pipelined structure (best measured) + bijective XCD swizzle (FETCH
// 73.8->24.6 MB). Schedule-space converged (~30% MfmaUtil at 1 block/CU): R4 fine
// phases and R8 faithful m201 8-phase both neutral-to-negative.
template <int EPI>
__global__ __launch_bounds__(512, 2) void gemm256(const bf16* __restrict__ A,
                                                  const bf16* __restrict__ BT,
                                                  bf16* __restrict__ Cb,
                                                  bf16* __restrict__ Pb,
                                                  int M, int N, int K) {
    __shared__ bf16 LA[4][8192];   // per buf: 256 rows x 32 k (64B rows), swizzled
    __shared__ bf16 LB[4][8192];
    int tid = threadIdx.x;
    int wave = tid >> 6, lane = tid & 63;
    int q = lane >> 4, ln16 = lane & 15;

    // ---- bijective XCD swizzle (m204): hardware linear id -> tile id ----
    int gx = gridDim.x, gy = gridDim.y, gz = gridDim.z;
    int L = blockIdx.x + gx * (blockIdx.y + gy * blockIdx.z);
    int nwg = gx * gy * gz;
    int qd = nwg >> 3, rd = nwg & 7;
    int xcd = L & 7, base = L >> 3;
    int wg = (xcd < rd ? xcd * (qd + 1) : rd * (qd + 1) + (xcd - rd) * qd) + base;
    int bxi = wg % gx, byi = (wg / gx) % gy, bzi = wg / (gx * gy);

    int bm = byi * 256, bn = bxi * 256;
    int wm = (wave >> 2) * 128, wn = (wave & 3) * 64;
    int ksz = K / gz;
    int kb = bzi * ksz;
    int NT = ksz >> 5;             // K-tiles of 32; NT even, >= 4

    // staging: 2 loads per matrix per K-tile; load l covers LDS bytes [l*8192, l*8192+8192)
    // LDS[x] holds element at swz(x); swz(o) = o ^ (((o>>7)&3)<<4)  (involution, 16B-preserving)
    int o0 = tid * 16, o1 = 8192 + tid * 16;
    int r0 = o0 >> 6, r1 = o1 >> 6;
    int c0 = (o0 & 63) ^ (((r0 >> 1) & 3) << 4);
    int c1 = (o1 & 63) ^ (((r1 >> 1) & 3) << 4);
    const bf16* pa0 = &A[(size_t)(bm + r0) * K + kb + (c0 >> 1)];
    const bf16* pa1 = &A[(size_t)(bm + r1) * K + kb + (c1 >> 1)];
    const bf16* pb0 = &BT[(size_t)(bn + r0) * K + kb + (c0 >> 1)];
    const bf16* pb1 = &BT[(size_t)(bn + r1) * K + kb + (c1 >> 1)];
    int d0 = wave * 512;           // element index of wave-uniform LDS dest, load 0
    int d1 = 4096 + wave * 512;    // load 1

    // fragment LDS byte offsets (swizzled), constant across K-tiles
    int aoff[8], boff[4];
#pragma unroll
    for (int i = 0; i < 8; ++i) {
        int r = wm + i * 16 + ln16;
        aoff[i] = (r * 64 + q * 16) ^ (((r >> 1) & 3) << 4);
    }
#pragma unroll
    for (int j = 0; j < 4; ++j) {
        int r = wn + j * 16 + ln16;
        boff[j] = (r * 64 + q * 16) ^ (((r >> 1) & 3) << 4);
    }

    f32x4 zf; zf[0] = zf[1] = zf[2] = zf[3] = 0.f;
    f32x4 acc[8][4];
#pragma unroll
    for (int i = 0; i < 8; ++i)
#pragma unroll
        for (int j = 0; j < 4; ++j) acc[i][j] = zf;

    auto STAGE = [&](int b, int koff) {
        gload_lds16(pa0 + koff, &LA[b][d0]);
        gload_lds16(pa1 + koff, &LA[b][d1]);
        gload_lds16(pb0 + koff, &LB[b][d0]);
        gload_lds16(pb1 + koff, &LB[b][d1]);
    };

#define RD_FRAGS(AV, BV, TT) do {                                             \
        const bf16* LAb_ = LA[(TT) & 3];                                      \
        const bf16* LBb_ = LB[(TT) & 3];                                      \
        _Pragma("unroll")                                                     \
        for (int j_ = 0; j_ < 4; ++j_) BV[j_] = *(const bf16x8*)&LBb_[boff[j_] >> 1]; \
        _Pragma("unroll")                                                     \
        for (int i_ = 0; i_ < 8; ++i_) AV[i_] = *(const bf16x8*)&LAb_[aoff[i_] >> 1]; \
    } while (0)

#define MFMA_ALL(AV, BV) do {                                                 \
        __builtin_amdgcn_s_setprio(1);                                        \
        _Pragma("unroll")                                                     \
        for (int i_ = 0; i_ < 8; ++i_)                                        \
            _Pragma("unroll")                                                 \
            for (int j_ = 0; j_ < 4; ++j_)                                    \
                acc[i_][j_] = __builtin_amdgcn_mfma_f32_16x16x32_bf16(AV[i_], BV[j_], acc[i_][j_], 0, 0, 0); \
        __builtin_amdgcn_s_setprio(0);                                        \
    } while (0)

    bf16x8 avX[8], bvX[4], avY[8], bvY[4];

    // prologue: stage K-tiles 0..2 (12 loads); wait tiles 0,1 (vmcnt(4) leaves S2); barrier
    STAGE(0, 0); STAGE(1, 32); STAGE(2, 64);
    asm volatile("s_waitcnt vmcnt(4)" ::: "memory");
    SBAR();
    RD_FRAGS(avX, bvX, 0);

    for (int t = 0; t < NT; t += 2) {
        // ---- even iter t: MFMA on X, prefetch frags(t+1) into Y ----
        if (t + 1 < NT) RD_FRAGS(avY, bvY, t + 1);
        if (t + 3 < NT) STAGE((t + 3) & 3, (t + 3) * 32);
        MFMA_ALL(avX, bvX);
        if (t + 3 < NT)      asm volatile("s_waitcnt vmcnt(4)" ::: "memory");
        else if (t + 2 < NT) asm volatile("s_waitcnt vmcnt(0)" ::: "memory");
        SBAR();
        // ---- odd iter t+1: MFMA on Y, prefetch frags(t+2) into X ----
        if (t + 2 < NT) RD_FRAGS(avX, bvX, t + 2);
        if (t + 4 < NT) STAGE((t + 4) & 3, (t + 4) * 32);
        MFMA_ALL(avY, bvY);
        if (t + 4 < NT)      asm volatile("s_waitcnt vmcnt(4)" ::: "memory");
        else if (t + 3 < NT) asm volatile("s_waitcnt vmcnt(0)" ::: "memory");
        SBAR();
    }
#undef RD_FRAGS
#undef MFMA_ALL

    size_t pbase = (size_t)bzi * ((size_t)M * N);
#pragma unroll
    for (int i = 0; i < 8; ++i)
#pragma unroll
        for (int r = 0; r < 4; ++r) {
            int row = bm + wm + i * 16 + q * 4 + r;
#pragma unroll
            for (int j = 0; j < 4; ++j) {
                int col = bn + wn + j * 16 + ln16;
                size_t idx = (size_t)row * N + col;
                float v = acc[i][j][r];
                if (EPI == 0) Cb[idx] = __float2bfloat16(v);
                else          Pb[pbase + idx] = __float2bfloat16(v);
            }
        }
}

// ---------------- split-K reduce kernels (bf16 partials) ----------------
__global__ __launch_bounds__(256) void reduce_plain(const bf16* __restrict__ P, int ns, size_t MN,
                                                    bf16* __restrict__ O) {
    size_t i = ((size_t)blockIdx.x * 256 + threadIdx.x) * 4;
    float s[4] = {0.f, 0.f, 0.f, 0.f};
    for (int k = 0; k < ns; ++k) {
        ushort4 p = *reinterpret_cast<const ushort4*>(&P[(size_t)k * MN + i]);
        s[0] += bits2f(p.x); s[1] += bits2f(p.y); s[2] += bits2f(p.z); s[3] += bits2f(p.w);
    }
    bf16 r[4];
#pragma unroll
    for (int j = 0; j < 4; ++j) r[j] = __float2bfloat16(s[j]);
    *reinterpret_cast<ushort4*>(&O[i]) = *reinterpret_cast<ushort4*>(r);
}

__global__ __launch_bounds__(256) void reduce_gate(const bf16* __restrict__ P, int ns, size_t MN,
                                                   const bf16* __restrict__ XZ, bf16* __restrict__ YM) {
    size_t i = ((size_t)blockIdx.x * 256 + threadIdx.x) * 4;  // over T_TOK*DI
    float s[4] = {0.f, 0.f, 0.f, 0.f};
    for (int k = 0; k < ns; ++k) {
        ushort4 p = *reinterpret_cast<const ushort4*>(&P[(size_t)k * MN + i]);
        s[0] += bits2f(p.x); s[1] += bits2f(p.y); s[2] += bits2f(p.z); s[3] += bits2f(p.w);
    }
    int t = (int)(i >> 11), c = (int)(i & (DI - 1));
    const bf16* zp = &XZ[(size_t)t * N2 + DI + c];
    bf16 r[4];
#pragma unroll
    for (int j = 0; j < 4; ++j) {
        float z = b2f(zp[j]);
        r[j] = __float2bfloat16(s[j] * (z / (1.f + __expf(-z))));
    }
    *reinterpret_cast<ushort4*>(&YM[i]) = *reinterpret_cast<ushort4*>(r);
}

__global__ __launch_bounds__(256) void reduce_out(const bf16* __restrict__ P, int ns, size_t MN,
                                                  const float* __restrict__ x, float* __restrict__ out) {
    size_t i = ((size_t)blockIdx.x * 256 + threadIdx.x) * 4;  // over T_TOK*DM
    float s[4] = {0.f, 0.f, 0.f, 0.f};
    for (int k = 0; k < ns; ++k) {
        ushort4 p = *reinterpret_cast<const ushort4*>(&P[(size_t)k * MN + i]);
        s[0] += bits2f(p.x); s[1] += bits2f(p.y); s[2] += bits2f(p.z); s[3] += bits2f(p.w);
    }
    float4 xv = *reinterpret_cast<const float4*>(&x[i]);
    float4 o = {s[0] + xv.x, s[1] + xv.y, s[2] + xv.z, s[3] + xv.w};
    *reinterpret_cast<float4*>(&out[i]) = o;
}

__global__ __launch_bounds__(256) void reduce_xdbl(const bf16* __restrict__ P, int ns, size_t MN,
                                                   float* __restrict__ XDP, bf16* __restrict__ XDdt) {
    size_t i = ((size_t)blockIdx.x * 256 + threadIdx.x) * 4;  // over 2*T_TOK*128
    float s[4] = {0.f, 0.f, 0.f, 0.f};
    for (int k = 0; k < ns; ++k) {
        ushort4 p = *reinterpret_cast<const ushort4*>(&P[(size_t)k * MN + i]);
        s[0] += bits2f(p.x); s[1] += bits2f(p.y); s[2] += bits2f(p.z); s[3] += bits2f(p.w);
    }
    float4 o = {s[0], s[1], s[2], s[3]};
    *reinterpret_cast<float4*>(&XDP[i]) = o;
    int col = (int)(i & (XDP_LD - 1));
    if (col < DTR) {
        size_t row = i >> 7;
        bf16 r[4];
#pragma unroll
        for (int j = 0; j < 4; ++j) r[j] = __float2bfloat16(s[j]);
        *reinterpret_cast<ushort4*>(&XDdt[row * DTR + col]) = *reinterpret_cast<ushort4*>(r);
    }
}

// ---------------- dt GEMM fallback (vector, K=64, reads XDP fp32) ----------------
__global__ __launch_bounds__(256) void gemm_dt(const float* __restrict__ A,   // lda=128
                                               const float* __restrict__ Bw,  // 64 x 2048 f32
                                               const float* __restrict__ bias,
                                               bf16* __restrict__ Cb, int M, int N) {
    __shared__ float As[16][68];
    __shared__ float Bs[16][68];
    int tid = threadIdx.x;
    int bm = blockIdx.y * 64, bn = blockIdx.x * 64;
    int tx = tid & 15, ty = tid >> 4;
    float acc[4][4];
#pragma unroll
    for (int i = 0; i < 4; ++i)
#pragma unroll
        for (int j = 0; j < 4; ++j) acc[i][j] = 0.f;
    int arow = tid >> 2, acg = (tid & 3) * 4;
    int brow = tid >> 4, bcol = (tid & 15) * 4;
    for (int k0 = 0; k0 < DTR; k0 += 16) {
        float4 av = *reinterpret_cast<const float4*>(&A[(size_t)(bm + arow) * XDP_LD + k0 + acg]);
        As[acg + 0][arow] = av.x; As[acg + 1][arow] = av.y;
        As[acg + 2][arow] = av.z; As[acg + 3][arow] = av.w;
        float4 bv = *reinterpret_cast<const float4*>(&Bw[(size_t)(k0 + brow) * N + bn + bcol]);
        Bs[brow][bcol + 0] = bv.x; Bs[brow][bcol + 1] = bv.y;
        Bs[brow][bcol + 2] = bv.z; Bs[brow][bcol + 3] = bv.w;
        __syncthreads();
#pragma unroll
        for (int kk = 0; kk < 16; ++kk) {
            float4 a = *reinterpret_cast<const float4*>(&As[kk][ty * 4]);
            float4 b = *reinterpret_cast<const float4*>(&Bs[kk][tx * 4]);
            acc[0][0] += a.x * b.x; acc[0][1] += a.x * b.y; acc[0][2] += a.x * b.z; acc[0][3] += a.x * b.w;
            acc[1][0] += a.y * b.x; acc[1][1] += a.y * b.y; acc[1][2] += a.y * b.z; acc[1][3] += a.y * b.w;
            acc[2][0] += a.z * b.x; acc[2][1] += a.z * b.y; acc[2][2] += a.z * b.z; acc[2][3] += a.z * b.w;
            acc[3][0] += a.w * b.x; acc[3][1] += a.w * b.y; acc[3][2] += a.w * b.z; acc[3][3] += a.w * b.w;
        }
        __syncthreads();
    }
    int row0 = bm + ty * 4, col0 = bn + tx * 4;
#pragma unroll
    for (int i = 0; i < 4; ++i)
#pragma unroll
        for (int j = 0; j < 4; ++j) {
            float v = acc[i][j] + bias[col0 + j];
            Cb[(size_t)(row0 + i) * N + col0 + j] = __float2bfloat16(softplus_fast(v));
        }
}

// ---------------- depthwise causal conv (fwd) + anti-causal (bwd) + SiLU ----------------
// Vectorized (G13): 1 thread = 8 consecutive channels; taps are bf16x8 16B loads,
// weights contiguous float4s, outputs bf16x8.
__global__ __launch_bounds__(256) void conv_kernel(const bf16* __restrict__ XZ,
                                                   const float* __restrict__ wf, const float* __restrict__ bf_,
                                                   const float* __restrict__ wb, const float* __restrict__ bb_,
                                                   bf16* __restrict__ XCF, bf16* __restrict__ XCB) {
    int idx = blockIdx.x * 256 + threadIdx.x;   // over T_TOK*DI/8
    int cg = idx & (DI / 8 - 1);
    int c0 = cg * 8;
    int g = idx >> 8;                 // token index
    int l = g & (SEQ - 1);
    int b = g >> 10;
    float sf[8], sb[8];
    float4 wfv[8], wbv[8];
#pragma unroll
    for (int u = 0; u < 8; ++u) {
        wfv[u] = *(const float4*)&wf[(c0 + u) * 4];
        wbv[u] = *(const float4*)&wb[(c0 + u) * 4];
        sf[u] = bf_[c0 + u];
        sb[u] = bb_[c0 + u];
    }
#pragma unroll
    for (int j = 0; j < 4; ++j) {
        int lf = l - 3 + j;
        if (lf >= 0) {
            bf16x8 v = *(const bf16x8*)&XZ[((size_t)(b * SEQ + lf)) * N2 + c0];
#pragma unroll
            for (int u = 0; u < 8; ++u) {
                float w = (j == 0) ? wfv[u].x : (j == 1) ? wfv[u].y : (j == 2) ? wfv[u].z : wfv[u].w;
                sf[u] += w * bits2f((unsigned short)v[u]);
            }
        }
        int lb = l + 3 - j;
        if (lb < SEQ) {
            bf16x8 v = *(const bf16x8*)&XZ[((size_t)(b * SEQ + lb)) * N2 + c0];
#pragma unroll
            for (int u = 0; u < 8; ++u) {
                float w = (j == 0) ? wbv[u].x : (j == 1) ? wbv[u].y : (j == 2) ? wbv[u].z : wbv[u].w;
                sb[u] += w * bits2f((unsigned short)v[u]);
            }
        }
    }
    bf16 rf[8], rb[8];
#pragma unroll
    for (int u = 0; u < 8; ++u) {
        rf[u] = __float2bfloat16(sf[u] / (1.f + __expf(-sf[u])));
        rb[u] = __float2bfloat16(sb[u] / (1.f + __expf(-sb[u])));
    }
    size_t o = (size_t)g * DI + c0;
    *(bf16x8*)&XCF[o] = *(bf16x8*)rf;
    *(bf16x8*)&XCB[o] = *(bf16x8*)rb;
}

// ---------------- chunked selective scan (3 kernels, HW stream barriers) ----------------
// NC=32 (CLEN=32). 2 threads per channel (8 states each); DT/XC tiles bulk-staged in LDS.
// NEW: power-chain dA. The problem's A_log = log(tile(arange(1..16))) gives
// A[c][n] = -(n+1), so exp(dt*A[n]) = r^(n+1) with r = exp(dt*aunit), aunit = A[0]/1.
// Per token: 1 exp + ~11 full-rate mults replaces 8 quarter-rate exps. A runtime
// per-thread pattern check (integer exponent ratios) falls back to the generic
// 8-exp path, so correctness never depends on the input pattern.
template <int NC, bool FINAL>
__global__ __launch_bounds__(256) void scan_chunk(const bf16* __restrict__ DTF_, const bf16* __restrict__ DTB_,
                                                  const bf16* __restrict__ XCF_, const bf16* __restrict__ XCB_,
                                                  const float* __restrict__ XDP,
                                                  const float* __restrict__ Af, const float* __restrict__ Ab,
                                                  const float* __restrict__ Df, const float* __restrict__ Db,
                                                  float* __restrict__ HLOC, float* __restrict__ SUMDT,
                                                  bf16* __restrict__ YCAT) {
    constexpr int CL = SEQ / NC;
    __shared__ float bsl[CL][32];
    __shared__ bf16 dtl[CL][128];
    __shared__ bf16 xcl[CL][128];
    int tid = threadIdx.x;
    int sg = tid & 1;                          // state group: states sg*8 .. sg*8+7
    int cl = tid >> 1;                         // channel local 0..127
    int cbase = blockIdx.x * 128;
    int c = cbase + cl;
    int b = blockIdx.y;
    int dir = (int)blockIdx.z >= NC;
    int chunk = blockIdx.z - dir * NC;
    const bf16* DT = dir ? DTB_ : DTF_;
    const bf16* XC = dir ? XCB_ : XCF_;
    // stage B/C rows for the whole chunk: CL tokens x 32 floats
    for (int i = tid; i < CL * 8; i += 256) {
        int it = i >> 3, j4 = (i & 7) * 4;
        int sit = chunk * CL + it;
        int l = dir ? (SEQ - 1 - sit) : sit;
        size_t row = (size_t)dir * T_TOK + (size_t)b * SEQ + l;
        *(float4*)&bsl[it][j4] = *(const float4*)&XDP[row * XDP_LD + DTR + j4];
    }
    // stage DT/XC tiles: CL tokens x 128 channels, 16B chunks, fully coalesced
    for (int ch = tid; ch < CL * 16; ch += 256) {
        int it = ch >> 4, of = (ch & 15) * 8;
        int sit = chunk * CL + it;
        int l = dir ? (SEQ - 1 - sit) : sit;
        size_t g = (size_t)b * SEQ + l;
        *(bf16x8*)&dtl[it][of] = *(const bf16x8*)&DT[g * DI + cbase + of];
        *(bf16x8*)&xcl[it][of] = *(const bf16x8*)&XC[g * DI + cbase + of];
    }
    const float* Al = dir ? Ab : Af;
    int sg8 = sg * 8;
    float A[8];
#pragma unroll
    for (int n = 0; n < 8; ++n) A[n] = -__expf(Al[c * NST + sg8 + n]);
    // pattern check: A[n] == aunit * (sg8+1+n) with aunit = A[0]/(sg8+1)?
    float aunit = A[0] / (float)(sg8 + 1);
    bool fastp = true;
#pragma unroll
    for (int n = 1; n < 8; ++n) {
        float k = A[n] / aunit;
        fastp = fastp && (fabsf(k - (float)(sg8 + 1 + n)) < 1e-3f);
    }
    size_t base = ((((size_t)dir * BATCH + b) * NC + chunk) * DI + c);
    float h[8];
    float Dv = 0.f;
    if (FINAL) {
#pragma unroll
        for (int n = 0; n < 8; ++n) h[n] = HLOC[base * NST + sg8 + n];
        Dv = (dir ? Db : Df)[c];
    } else {
#pragma unroll
        for (int n = 0; n < 8; ++n) h[n] = 0.f;
    }
    __syncthreads();
    float sumdt = 0.f;
    for (int it = 0; it < CL; ++it) {
        int sit = chunk * CL + it;
        int l = dir ? (SEQ - 1 - sit) : sit;
        size_t g = (size_t)b * SEQ + l;
        float dt = b2f(dtl[it][cl]);
        float xc = b2f(xcl[it][cl]);
        float dtxc = dt * xc;
        const float* bs = &bsl[it][sg8];
        float da[8];
        if (fastp) {
            float r = __expf(dt * aunit);
            float p = r;
            if (sg) { float r2 = r * r; float r4 = r2 * r2; float r8 = r4 * r4; p = r8 * r; }
            da[0] = p;
#pragma unroll
            for (int n = 1; n < 8; ++n) { p *= r; da[n] = p; }
        } else {
#pragma unroll
            for (int n = 0; n < 8; ++n) da[n] = __expf(dt * A[n]);
        }
        if (FINAL) {
            float y = 0.f;
#pragma unroll
            for (int n = 0; n < 8; ++n) {
                h[n] = da[n] * h[n] + dtxc * bs[n];
                y += h[n] * bs[NST + n];
            }
            y += __shfl_xor(y, 1);
            if (!sg) YCAT[g * N2 + dir * DI + c] = __float2bfloat16(y + xc * Dv);
        } else {
            sumdt += dt;
#pragma unroll
            for (int n = 0; n < 8; ++n)
                h[n] = da[n] * h[n] + dtxc * bs[n];
        }
    }
    if (!FINAL) {
#pragma unroll
        for (int n = 0; n < 8; ++n) HLOC[base * NST + sg8 + n] = h[n];
        if (!sg) SUMDT[base] = sumdt;
    }
}

// phase B: sequential combine over chunks; rewrites HLOC[k] with carry-in h for chunk k
__global__ __launch_bounds__(256) void scan_combine(float* __restrict__ HLOC,
                                                    const float* __restrict__ SUMDT,
                                                    const float* __restrict__ Af,
                                                    const float* __restrict__ Ab, int nchunk) {
    int idx = blockIdx.x * 256 + threadIdx.x;   // over 2*BATCH*DI*NST = 131072
    int n = idx & 15;
    int c = (idx >> 4) & (DI - 1);
    int b = (idx >> 15) & 1;
    int dir = idx >> 16;
    float A = -__expf((dir ? Ab : Af)[c * NST + n]);
    float h = 0.f;
    for (int k = 0; k < nchunk; ++k) {
        size_t base = ((((size_t)dir * BATCH + b) * nchunk + k) * DI + c);
        float P = __expf(A * SUMDT[base]);
        float hl = HLOC[base * NST + n];
        HLOC[base * NST + n] = h;
        h = P * h + hl;
    }
}

// ---------------- gating fallback: YM *= silu(z) ----------------
__global__ __launch_bounds__(256) void gate_kernel(bf16* __restrict__ YM, const bf16* __restrict__ XZ) {
    int idx = blockIdx.x * 256 + threadIdx.x;  // over T_TOK*DI
    int t = idx >> 11;
    int c = idx & (DI - 1);
    float z = b2f(XZ[(size_t)t * N2 + DI + c]);
    float y = b2f(YM[idx]);
    YM[idx] = __float2bfloat16(y * (z / (1.f + __expf(-z))));
}

extern "C" void kernel_launch(void* const* d_in, const int* in_sizes, int n_in,
                              void* d_out, int out_size, void* d_ws, size_t ws_size,
                              hipStream_t stream) {
    const float* x       = (const float*)d_in[0];
    const float* gamma   = (const float*)d_in[1];
    const float* beta    = (const float*)d_in[2];
    const float* in_w    = (const float*)d_in[3];
    const float* conv_w  = (const float*)d_in[4];
    const float* conv_b  = (const float*)d_in[5];
    const float* xproj_w = (const float*)d_in[6];
    const float* dt_w    = (const float*)d_in[7];
    const float* dt_b    = (const float*)d_in[8];
    const float* A_log   = (const float*)d_in[9];
    const float* D_skip  = (const float*)d_in[10];
    const float* conv_w_b  = (const float*)d_in[11];
    const float* conv_b_b  = (const float*)d_in[12];
    const float* xproj_w_b = (const float*)d_in[13];
    const float* dt_w_b    = (const float*)d_in[14];
    const float* dt_b_b    = (const float*)d_in[15];
    const float* A_log_b   = (const float*)d_in[16];
    const float* D_skip_b  = (const float*)d_in[17];
    const float* merge_w   = (const float*)d_in[18];
    const float* out_w     = (const float*)d_in[19];
    float* out = (float*)d_out;

    // ---- base workspace layout ----
    char* w = (char*)d_ws;
    size_t off = 0;
    bf16* H       = (bf16*)(w + off); off += (size_t)T_TOK * DM * 2;          //  4.19 MB
    bf16* XZ      = (bf16*)(w + off); off += (size_t)T_TOK * N2 * 2;          // 16.78 MB
    bf16* XCF     = (bf16*)(w + off); off += (size_t)T_TOK * DI * 2;          //  8.39 MB
    bf16* XCB     = (bf16*)(w + off); off += (size_t)T_TOK * DI * 2;          //  8.39 MB
    bf16* XPF     = (bf16*)(w + off); off += (size_t)XDP_LD * DI * 2;         //  0.52 MB
    bf16* XPB     = (bf16*)(w + off); off += (size_t)XDP_LD * DI * 2;         //  0.52 MB
    float* XDP    = (float*)(w + off); off += (size_t)2 * T_TOK * XDP_LD * 4; //  2.10 MB
    bf16* DTF     = (bf16*)(w + off); off += (size_t)T_TOK * DI * 2;          //  8.39 MB
    bf16* DTB     = (bf16*)(w + off); off += (size_t)T_TOK * DI * 2;          //  8.39 MB (contig after DTF)
    bf16* YCAT    = (bf16*)(w + off); off += (size_t)T_TOK * N2 * 2;          // 16.78 MB
    bf16* in_wT   = (bf16*)(w + off); off += (size_t)N2 * DM * 2;             //  8.39 MB
    bf16* out_wT  = (bf16*)(w + off); off += (size_t)DM * DI * 2;             //  4.19 MB
    bf16* merge_wT= (bf16*)(w + off); off += (size_t)DI * N2 * 2;             // 16.78 MB
    bf16* dtwT    = (bf16*)(w + off); off += (size_t)2 * DI * DTR * 2;        //  0.52 MB
    bf16* XDdt    = (bf16*)(w + off); off += (size_t)2 * T_TOK * DTR * 2;     //  0.52 MB
    // PART region: time-shared {xz partials | xdbl partials | HLOC+SUMDT | merge partials | out partials}
    char* PART = w + off;
    size_t avail = (ws_size > off) ? ws_size - off : 0;

    float* HLOC  = (float*)PART;                                              // 8.39 MB (NCHUNK=32)
    float* SUMDT = (float*)(PART + (size_t)2 * BATCH * NCHUNK * DI * NST * 4);// +0.52 MB
    bf16* Pb     = (bf16*)PART;                                               // split-K bf16 partials
    bf16* YM     = DTF;    // alias: DTF dead after scan C

    size_t MNm = (size_t)T_TOK * DI;          // merge partial elems
    size_t MNo = (size_t)T_TOK * DM;          // out partial elems
    size_t MNx = (size_t)2 * T_TOK * XDP_LD;  // xdbl partial elems
    size_t MNz = (size_t)T_TOK * N2;          // xz partial elems
    int s_merge = (avail >= 4 * MNm * 2) ? 4 : (avail >= 2 * MNm * 2) ? 2 : 0;
    int s_out   = (avail >= 4 * MNo * 2) ? 4 : (avail >= 2 * MNo * 2) ? 2 : 0;
    int s_xdbl  = (avail >= 16 * MNx * 2) ? 16 : (avail >= 8 * MNx * 2) ? 8 : (avail >= 4 * MNx * 2) ? 4 : 0;
    int s_xz    = (avail >= 2 * MNz * 2) ? 2 : 0;

    // 1. mega prep: LN + in_wT + out_wT + merge_wT + xproj/dtw
    prep_mega<<<LN_BLKS + INW_T + OUTW_T + MRGW_T + SMALL_BLK, 256, 0, stream>>>(
        x, gamma, beta, H, in_w, in_wT, out_w, out_wT, merge_w, merge_wT,
        xproj_w, xproj_w_b, XPF, XPB, dt_w, dt_w_b, dtwT);
    // 2. xz = H @ in_w  (M=2048, N=4096, K=1024) -> XZ bf16
    if (s_xz) {
        gemm256<3><<<dim3(N2 / 256, T_TOK / 256, s_xz), 512, 0, stream>>>(
            H, in_wT, nullptr, Pb, T_TOK, N2, DM);
        reduce_plain<<<(int)(MNz / 4 / 256), 256, 0, stream>>>(Pb, s_xz, MNz, XZ);
    } else {
        mfma_gemm<0><<<dim3(N2 / 128, T_TOK / 128), 256, 0, stream>>>(
            H, in_wT, in_wT, 1 << 30, XZ, nullptr, nullptr, nullptr, nullptr, nullptr, T_TOK, N2, DM);
    }
    // 3. depthwise conv + silu, both dirs (vectorized: 8 channels/thread)
    conv_kernel<<<(T_TOK * DI / 8) / 256, 256, 0, stream>>>(XZ, conv_w, conv_b, conv_w_b, conv_b_b, XCF, XCB);
    // 4. x_dbl (padded): XDP = [XCF;XCB] @ xproj (M=4096, N=128, K=2048), B per dir
    if (s_xdbl) {
        mfma_gemm<3><<<dim3(1, (2 * T_TOK) / 128, s_xdbl), 256, 0, stream>>>(
            XCF, XPF, XPB, (T_TOK / 128), nullptr, nullptr, nullptr, Pb, nullptr, nullptr,
            2 * T_TOK, XDP_LD, DI);
        reduce_xdbl<<<(int)(MNx / 4 / 256), 256, 0, stream>>>(Pb, s_xdbl, MNx, XDP, XDdt);
        // 5. dt = softplus(XDdt @ dt_w + dt_b) via MFMA (M=4096 both dirs, N=2048, K=64)
        mfma_gemm<4><<<dim3(DI / 128, (2 * T_TOK) / 128), 256, 0, stream>>>(
            XDdt, dtwT, dtwT + (size_t)DI * DTR, (T_TOK / 128), DTF, nullptr, nullptr, nullptr,
            dt_b, dt_b_b, 2 * T_TOK, DI, DTR);
    } else {
        mfma_gemm<2><<<dim3(1, (2 * T_TOK) / 128), 256, 0, stream>>>(
            XCF, XPF, XPB, (T_TOK / 128), nullptr, nullptr, XDP, nullptr, nullptr, nullptr,
            2 * T_TOK, XDP_LD, DI);
        gemm_dt<<<dim3(DI / 64, T_TOK / 64), 256, 0, stream>>>(XDP, dt_w, dt_b, DTF, T_TOK, DI);
        gemm_dt<<<dim3(DI / 64, T_TOK / 64), 256, 0, stream>>>(XDP + (size_t)T_TOK * XDP_LD, dt_w_b, dt_b_b, DTB, T_TOK, DI);
    }
    // 6-8. chunked scan (3 kernels; stream boundaries are the grid barriers)
    scan_chunk<NCHUNK, false><<<dim3(DI / 128, BATCH, 2 * NCHUNK), 256, 0, stream>>>(
        DTF, DTB, XCF, XCB, XDP, A_log, A_log_b, D_skip, D_skip_b, HLOC, SUMDT, YCAT);
    scan_combine<<<(2 * BATCH * DI * NST) / 256, 256, 0, stream>>>(HLOC, SUMDT, A_log, A_log_b, NCHUNK);
    scan_chunk<NCHUNK, true><<<dim3(DI / 128, BATCH, 2 * NCHUNK), 256, 0, stream>>>(
        DTF, DTB, XCF, XCB, XDP, A_log, A_log_b, D_skip, D_skip_b, HLOC, SUMDT, YCAT);
    // 9. YM = silu(z) * (YCAT @ merge_w) (M=2048, N=2048, K=4096)
    if (s_merge) {
        gemm256<3><<<dim3(DI / 256, T_TOK / 256, s_merge), 512, 0, stream>>>(
            YCAT, merge_wT, nullptr, Pb, T_TOK, DI, N2);
        reduce_gate<<<(int)(MNm / 4 / 256), 256, 0, stream>>>(Pb, s_merge, MNm, XZ, YM);
    } else {
        mfma_gemm<0><<<dim3(DI / 128, T_TOK / 128), 256, 0, stream>>>(
            YCAT, merge_wT, merge_wT, 1 << 30, YM, nullptr, nullptr, nullptr, nullptr, nullptr,
            T_TOK, DI, N2);
        gate_kernel<<<(T_TOK * DI) / 256, 256, 0, stream>>>(YM, XZ);
    }
    // 10. out = x + YM @ out_w (M=2048, N=1024, K=2048), f32
    if (s_out) {
        mfma_gemm<3><<<dim3(DM / 128, T_TOK / 128, s_out), 256, 0, stream>>>(
            YM, out_wT, out_wT, 1 << 30, nullptr, nullptr, nullptr, Pb, nullptr, nullptr,
            T_TOK, DM, DI);
        reduce_out<<<(int)(MNo / 4 / 256), 256, 0, stream>>>(Pb, s_out, MNo, x, out);
    } else {
        mfma_gemm<1><<<dim3(DM / 128, T_TOK / 128), 256, 0, stream>>>(
            YM, out_wT, out_wT, 1 << 30, nullptr, x, out, nullptr, nullptr, nullptr,
            T_TOK, DM, DI);
    }
}

// Round 12
// 387.472 us; speedup vs baseline: 1.0542x; 1.0015x over previous
//
#include <hip/hip_runtime.h>
#include <hip/hip_bf16.h>
#include <math.h>

typedef __hip_bfloat16 bf16;
typedef unsigned int u32;
typedef __attribute__((ext_vector_type(8))) short bf16x8;
typedef __attribute__((ext_vector_type(4))) float f32x4;

#define BATCH 2
#define SEQ 1024
#define DM 1024
#define DI 2048
#define NST 16
#define DTR 64
#define XDN 96          // dt_rank + 2*N = 64+32
#define XDP_LD 128      // padded x_dbl row
#define T_TOK 2048      // BATCH*SEQ
#define N2 4096         // 2*DI
#define NCHUNK 32
#define CLEN 32

static __device__ __forceinline__ float b2f(bf16 v) { return __bfloat162float(v); }
static __device__ __forceinline__ float bits2f(unsigned short u) {
    return __uint_as_float(((unsigned)u) << 16);
}

// fast softplus: 2 HW transcendentals instead of libm log1pf (branchy, ~5x VALU)
static __device__ __forceinline__ float softplus_fast(float t) {
    return (t > 20.f) ? t : __logf(1.f + __expf(t));
}

// ---- async global->LDS, 16 bytes per lane; LDS dest must be wave-uniform base ----
static __device__ __forceinline__ void gload_lds16(const void* g, void* l) {
    __builtin_amdgcn_global_load_lds((__attribute__((address_space(1))) u32*)(size_t)g,
                                     (__attribute__((address_space(3))) u32*)l, 16, 0, 0);
}

// compiler memory fence + raw barrier (no vmcnt drain, unlike __syncthreads)
#define SBAR() do { asm volatile("" ::: "memory"); __builtin_amdgcn_s_barrier(); asm volatile("" ::: "memory"); } while (0)

// ---- 32x32 LDS tile transpose helper: in f32 [K][N] -> out bf16 [N][K] ----
static __device__ void tileT(const float* __restrict__ in, bf16* __restrict__ out,
                             int K, int N, int t, float (*tb)[33]) {
    int nt = N >> 5;
    int bx = (t % nt) << 5, by = (t / nt) << 5;
    int tx = threadIdx.x & 31, r0 = threadIdx.x >> 5;
#pragma unroll
    for (int r = r0; r < 32; r += 8)
        tb[r][tx] = in[(size_t)(by + r) * N + bx + tx];
    __syncthreads();
#pragma unroll
    for (int r = r0; r < 32; r += 8)
        out[(size_t)(bx + r) * K + by + tx] = __float2bfloat16(tb[tx][r]);
}

#define LN_BLKS   T_TOK                       // 2048
#define INW_T     ((N2 / 32) * (DM / 32))     // 4096
#define OUTW_T    ((DM / 32) * (DI / 32))     // 2048
#define MRGW_T    ((DI / 32) * (N2 / 32))     // 8192
#define SMALL_BLK ((2 * XDP_LD * DI + 2 * DI * DTR) / 256)  // 3072

// ---------------- prep_mega: LN + all weight preps ----------------
__global__ __launch_bounds__(256) void prep_mega(const float* __restrict__ x,
                                                 const float* __restrict__ gamma,
                                                 const float* __restrict__ beta,
                                                 bf16* __restrict__ H,
                                                 const float* __restrict__ in_w, bf16* __restrict__ in_wT,
                                                 const float* __restrict__ out_w, bf16* __restrict__ out_wT,
                                                 const float* __restrict__ merge_w, bf16* __restrict__ merge_wT,
                                                 const float* __restrict__ xpf, const float* __restrict__ xpb,
                                                 bf16* __restrict__ XPF, bf16* __restrict__ XPB,
                                                 const float* __restrict__ dtwf, const float* __restrict__ dtwb,
                                                 bf16* __restrict__ dtwT) {
    __shared__ float tbuf[32][33];
    __shared__ float red[8];
    int bid = blockIdx.x;
    int tid = threadIdx.x;

    if (bid < LN_BLKS) {
        // ---- LayerNorm, one token per block ----
        int t = bid;
        float xv[4];
        float s = 0.f, s2 = 0.f;
#pragma unroll
        for (int k = 0; k < 4; ++k) {
            float v = x[(size_t)t * DM + k * 256 + tid];
            xv[k] = v; s += v; s2 += v * v;
        }
#pragma unroll
        for (int off = 32; off; off >>= 1) {
            s  += __shfl_down(s, off);
            s2 += __shfl_down(s2, off);
        }
        int wid = tid >> 6, lane = tid & 63;
        if (!lane) { red[wid] = s; red[4 + wid] = s2; }
        __syncthreads();
        if (tid == 0) {
            float S = red[0] + red[1] + red[2] + red[3];
            float S2 = red[4] + red[5] + red[6] + red[7];
            float mu = S * (1.f / DM);
            float var = S2 * (1.f / DM) - mu * mu;
            red[0] = mu;
            red[1] = rsqrtf(var + 1e-5f);
        }
        __syncthreads();
        float mu = red[0], rs = red[1];
#pragma unroll
        for (int k = 0; k < 4; ++k) {
            int i = k * 256 + tid;
            H[(size_t)t * DM + i] = __float2bfloat16((xv[k] - mu) * rs * gamma[i] + beta[i]);
        }
        return;
    }
    bid -= LN_BLKS;
    if (bid < INW_T)  { tileT(in_w, in_wT, DM, N2, bid, tbuf); return; }
    bid -= INW_T;
    if (bid < OUTW_T) { tileT(out_w, out_wT, DI, DM, bid, tbuf); return; }
    bid -= OUTW_T;
    if (bid < MRGW_T) { tileT(merge_w, merge_wT, N2, DI, bid, tbuf); return; }
    bid -= MRGW_T;
    // small: xproj pad-transpose + dt_w transpose
    int idx = bid * 256 + tid;
    if (idx < 2 * XDP_LD * DI) {
        int dir = idx >= XDP_LD * DI;
        int i = idx - dir * (XDP_LD * DI);
        int n = i >> 11;
        int k = i & (DI - 1);
        float v = (n < XDN) ? (dir ? xpb : xpf)[k * XDN + n] : 0.f;
        (dir ? XPB : XPF)[i] = __float2bfloat16(v);
    } else {
        int j = idx - 2 * XDP_LD * DI;     // over 2*2048*64
        int dir = j >= DI * DTR;
        int e = j - dir * (DI * DTR);
        int n = e >> 6;
        int k = e & 63;
        dtwT[(size_t)dir * DI * DTR + n * DTR + k] =
            __float2bfloat16((dir ? dtwb : dtwf)[(size_t)k * DI + n]);
    }
}

// ---------------- MFMA GEMM: C(MxN) = A(MxK,bf16,row-major) * BT(NxK,bf16)^T ----------------
// 128x128 tile, BK=64, 4 waves each 64x64 (4x4 of 16x16x32 MFMA); split-K over gridDim.z
template <int EPI>
__global__ __launch_bounds__(256) void mfma_gemm(const bf16* __restrict__ A,
                                                 const bf16* __restrict__ BT,
                                                 const bf16* __restrict__ BT2, int bysplit,
                                                 bf16* __restrict__ Cb,
                                                 const float* __restrict__ resid,
                                                 float* __restrict__ outf,
                                                 bf16* __restrict__ Pb,
                                                 const float* __restrict__ bias1,
                                                 const float* __restrict__ bias2,
                                                 int M, int N, int K) {
    __shared__ bf16 As[8192];   // [kg 0..7][m 0..127][8]
    __shared__ bf16 Bs[8192];   // [kg 0..7][n 0..127][8]
    int tid = threadIdx.x;
    int wave = tid >> 6, lane = tid & 63;
    int q = lane >> 4, ln16 = lane & 15;
    int bm = blockIdx.y * 128, bn = blockIdx.x * 128;
    int wm = (wave >> 1) * 64, wn = (wave & 1) * 64;
    const bf16* Bt = ((int)blockIdx.y < bysplit) ? BT : BT2;

    int ks = K / gridDim.z;
    int kb = blockIdx.z * ks;

    f32x4 zf; zf[0] = zf[1] = zf[2] = zf[3] = 0.f;
    f32x4 acc[4][4];
#pragma unroll
    for (int i = 0; i < 4; ++i)
#pragma unroll
        for (int j = 0; j < 4; ++j) acc[i][j] = zf;

    for (int k0 = kb; k0 < kb + ks; k0 += 64) {
#pragma unroll
        for (int i = 0; i < 4; ++i) {
            int s = wave * 256 + i * 64 + lane;   // slot 0..1023
            int kg = s >> 7, m = s & 127;
            gload_lds16(&A[(size_t)(bm + m) * K + k0 + kg * 8], &As[(wave * 256 + i * 64) * 8]);
            gload_lds16(&Bt[(size_t)(bn + m) * K + k0 + kg * 8], &Bs[(wave * 256 + i * 64) * 8]);
        }
        __syncthreads();
#pragma unroll
        for (int kk = 0; kk < 2; ++kk) {
            bf16x8 af[4], bfr[4];
#pragma unroll
            for (int i = 0; i < 4; ++i) {
                af[i]  = *(const bf16x8*)&As[(((kk * 4 + q) * 128) + (wm + i * 16 + ln16)) * 8];
                bfr[i] = *(const bf16x8*)&Bs[(((kk * 4 + q) * 128) + (wn + i * 16 + ln16)) * 8];
            }
#pragma unroll
            for (int i = 0; i < 4; ++i)
#pragma unroll
                for (int j = 0; j < 4; ++j)
                    acc[i][j] = __builtin_amdgcn_mfma_f32_16x16x32_bf16(af[i], bfr[j], acc[i][j], 0, 0, 0);
        }
        __syncthreads();
    }

    size_t pbase = (size_t)blockIdx.z * M * N;
#pragma unroll
    for (int i = 0; i < 4; ++i)
#pragma unroll
        for (int r = 0; r < 4; ++r) {
            int row = bm + wm + i * 16 + q * 4 + r;
            const float* bias = (EPI == 4) ? ((row < T_TOK) ? bias1 : bias2) : nullptr;
#pragma unroll
            for (int j = 0; j < 4; ++j) {
                int col = bn + wn + j * 16 + ln16;
                size_t idx = (size_t)row * N + col;
                float v = acc[i][j][r];
                if (EPI == 0)      Cb[idx] = __float2bfloat16(v);
                else if (EPI == 1) outf[idx] = resid[idx] + v;
                else if (EPI == 2) outf[idx] = v;
                else if (EPI == 3) Pb[pbase + idx] = __float2bfloat16(v);
                else {
                    Cb[idx] = __float2bfloat16(softplus_fast(v + bias[col]));
                }
            }
        }
}

// ---------------- gemm256: 256x128 tile, 8 waves (4Mx2N, 64x64 each), BK=32 ----------------
// 2 blocks/CU occupancy experiment (R12): triple-buffered LDS (72KB/block -> 144KB/CU),
// __launch_bounds__(512,4) caps VGPR at 128 (acc=64). Simple schedule per K-page:
// {read frags ; stage page t+2 ; MFMA 16 ; counted vmcnt(3) ; barrier} - no reg
// pipelining; the co-resident block's MFMA covers this block's barrier/wait stalls
// (m114 inter-block overlap). XCD swizzle + zero-conflict swizzled LDS kept.
// Races: stage(t+2) writes buf (t+2)%3 == (t-1)%3, whose frag reads drained (lgkmcnt
// before MFMA) ahead of the barrier ending iter t-1. vmcnt(3) at end of iter t leaves
// only stage(t+2)'s 3 loads outstanding -> page t+1 is resident. Requires NT >= 2.
// EPI 0: bf16 store to Cb. EPI 3: bf16 partial store to Pb + blockIdx.z*M*N.
template <int EPI>
__global__ __launch_bounds__(512, 4) void gemm256(const bf16* __restrict__ A,
                                                  const bf16* __restrict__ BT,
                                                  bf16* __restrict__ Cb,
                                                  bf16* __restrict__ Pb,
                                                  int M, int N, int K) {
    __shared__ bf16 LA[3][8192];   // per buf: 256 rows x 32 k (64B rows), swizzled, 16KB
    __shared__ bf16 LB[3][4096];   // per buf: 128 rows x 32 k, swizzled, 8KB
    int tid = threadIdx.x;
    int wave = tid >> 6, lane = tid & 63;
    int q = lane >> 4, ln16 = lane & 15;

    // ---- bijective XCD swizzle (m204): hardware linear id -> tile id ----
    int gx = gridDim.x, gy = gridDim.y, gz = gridDim.z;
    int L = blockIdx.x + gx * (blockIdx.y + gy * blockIdx.z);
    int nwg = gx * gy * gz;
    int qd = nwg >> 3, rd = nwg & 7;
    int xcd = L & 7, base = L >> 3;
    int wg = (xcd < rd ? xcd * (qd + 1) : rd * (qd + 1) + (xcd - rd) * qd) + base;
    int bxi = wg % gx, byi = (wg / gx) % gy, bzi = wg / (gx * gy);

    int bm = byi * 256, bn = bxi * 128;
    int wm = (wave >> 1) * 64, wn = (wave & 1) * 64;
    int ksz = K / gz;
    int kb = bzi * ksz;
    int NT = ksz >> 5;             // K-pages of 32; NT >= 2

    // staging: A = 2 gloads/page (rows 0-127, 128-255), B = 1 gload/page (rows 0-127).
    // LDS[x] holds element at swz(x); swz keeps 16B chunks, XORs chunk slot with row
    // bits (zero measured conflicts). Source pre-swizzled accordingly.
    int rl = tid >> 2;                              // row within 128-row region
    int cB = ((tid & 3) * 16) ^ (((rl >> 1) & 3) << 4);  // swizzled byte col
    const bf16* pa0 = &A[(size_t)(bm + rl) * K + kb + (cB >> 1)];
    const bf16* pa1 = pa0 + (size_t)128 * K;        // (rl+128)>>1 & 3 unchanged (128%8==0... 64%4==0)
    const bf16* pb  = &BT[(size_t)(bn + rl) * K + kb + (cB >> 1)];
    int dA0 = wave * 512, dA1 = 4096 + wave * 512, dB = wave * 512;  // element dests

    // fragment LDS byte offsets (swizzled), constant across pages
    int aoff[4], boff[4];
#pragma unroll
    for (int i = 0; i < 4; ++i) {
        int r = wm + i * 16 + ln16;
        aoff[i] = r * 64 + ((q * 16) ^ (((r >> 1) & 3) << 4));
    }
#pragma unroll
    for (int j = 0; j < 4; ++j) {
        int r = wn + j * 16 + ln16;
        boff[j] = r * 64 + ((q * 16) ^ (((r >> 1) & 3) << 4));
    }

    f32x4 zf; zf[0] = zf[1] = zf[2] = zf[3] = 0.f;
    f32x4 acc[4][4];
#pragma unroll
    for (int i = 0; i < 4; ++i)
#pragma unroll
        for (int j = 0; j < 4; ++j) acc[i][j] = zf;

    auto STAGE = [&](int b, int t) {
        gload_lds16(pa0 + t * 32, &LA[b][dA0]);
        gload_lds16(pa1 + t * 32, &LA[b][dA1]);
        gload_lds16(pb  + t * 32, &LB[b][dB]);
    };

    // prologue: stage pages 0,1; wait page 0 (vmcnt(3) leaves page 1's 3 loads); barrier
    STAGE(0, 0); STAGE(1, 1);
    asm volatile("s_waitcnt vmcnt(3)" ::: "memory");
    SBAR();

    int bc = 0, bs = 2;
    for (int t = 0; t < NT; ++t) {
        const bf16* Ab = LA[bc];
        const bf16* Bb = LB[bc];
        bf16x8 af[4], bfr[4];
#pragma unroll
        for (int j = 0; j < 4; ++j) bfr[j] = *(const bf16x8*)&Bb[boff[j] >> 1];
#pragma unroll
        for (int i = 0; i < 4; ++i) af[i] = *(const bf16x8*)&Ab[aoff[i] >> 1];
        if (t + 2 < NT) STAGE(bs, t + 2);
        __builtin_amdgcn_s_setprio(1);
#pragma unroll
        for (int i = 0; i < 4; ++i)
#pragma unroll
            for (int j = 0; j < 4; ++j)
                acc[i][j] = __builtin_amdgcn_mfma_f32_16x16x32_bf16(af[i], bfr[j], acc[i][j], 0, 0, 0);
        __builtin_amdgcn_s_setprio(0);
        if (t + 2 < NT)      asm volatile("s_waitcnt vmcnt(3)" ::: "memory");
        else if (t + 1 < NT) asm volatile("s_waitcnt vmcnt(0)" ::: "memory");
        SBAR();
        bc = (bc == 2) ? 0 : bc + 1;
        bs = (bs == 2) ? 0 : bs + 1;
    }

    size_t pbase = (size_t)bzi * ((size_t)M * N);
#pragma unroll
    for (int i = 0; i < 4; ++i)
#pragma unroll
        for (int r = 0; r < 4; ++r) {
            int row = bm + wm + i * 16 + q * 4 + r;
#pragma unroll
            for (int j = 0; j < 4; ++j) {
                int col = bn + wn + j * 16 + ln16;
                size_t idx = (size_t)row * N + col;
                float v = acc[i][j][r];
                if (EPI == 0) Cb[idx] = __float2bfloat16(v);
                else          Pb[pbase + idx] = __float2bfloat16(v);
            }
        }
}

// ---------------- split-K reduce kernels (bf16 partials) ----------------
__global__ __launch_bounds__(256) void reduce_plain(const bf16* __restrict__ P, int ns, size_t MN,
                                                    bf16* __restrict__ O) {
    size_t i = ((size_t)blockIdx.x * 256 + threadIdx.x) * 4;
    float s[4] = {0.f, 0.f, 0.f, 0.f};
    for (int k = 0; k < ns; ++k) {
        ushort4 p = *reinterpret_cast<const ushort4*>(&P[(size_t)k * MN + i]);
        s[0] += bits2f(p.x); s[1] += bits2f(p.y); s[2] += bits2f(p.z); s[3] += bits2f(p.w);
    }
    bf16 r[4];
#pragma unroll
    for (int j = 0; j < 4; ++j) r[j] = __float2bfloat16(s[j]);
    *reinterpret_cast<ushort4*>(&O[i]) = *reinterpret_cast<ushort4*>(r);
}

__global__ __launch_bounds__(256) void reduce_gate(const bf16* __restrict__ P, int ns, size_t MN,
                                                   const bf16* __restrict__ XZ, bf16* __restrict__ YM) {
    size_t i = ((size_t)blockIdx.x * 256 + threadIdx.x) * 4;  // over T_TOK*DI
    float s[4] = {0.f, 0.f, 0.f, 0.f};
    for (int k = 0; k < ns; ++k) {
        ushort4 p = *reinterpret_cast<const ushort4*>(&P[(size_t)k * MN + i]);
        s[0] += bits2f(p.x); s[1] += bits2f(p.y); s[2] += bits2f(p.z); s[3] += bits2f(p.w);
    }
    int t = (int)(i >> 11), c = (int)(i & (DI - 1));
    const bf16* zp = &XZ[(size_t)t * N2 + DI + c];
    bf16 r[4];
#pragma unroll
    for (int j = 0; j < 4; ++j) {
        float z = b2f(zp[j]);
        r[j] = __float2bfloat16(s[j] * (z / (1.f + __expf(-z))));
    }
    *reinterpret_cast<ushort4*>(&YM[i]) = *reinterpret_cast<ushort4*>(r);
}

__global__ __launch_bounds__(256) void reduce_out(const bf16* __restrict__ P, int ns, size_t MN,
                                                  const float* __restrict__ x, float* __restrict__ out) {
    size_t i = ((size_t)blockIdx.x * 256 + threadIdx.x) * 4;  // over T_TOK*DM
    float s[4] = {0.f, 0.f, 0.f, 0.f};
    for (int k = 0; k < ns; ++k) {
        ushort4 p = *reinterpret_cast<const ushort4*>(&P[(size_t)k * MN + i]);
        s[0] += bits2f(p.x); s[1] += bits2f(p.y); s[2] += bits2f(p.z); s[3] += bits2f(p.w);
    }
    float4 xv = *reinterpret_cast<const float4*>(&x[i]);
    float4 o = {s[0] + xv.x, s[1] + xv.y, s[2] + xv.z, s[3] + xv.w};
    *reinterpret_cast<float4*>(&out[i]) = o;
}

__global__ __launch_bounds__(256) void reduce_xdbl(const bf16* __restrict__ P, int ns, size_t MN,
                                                   float* __restrict__ XDP, bf16* __restrict__ XDdt) {
    size_t i = ((size_t)blockIdx.x * 256 + threadIdx.x) * 4;  // over 2*T_TOK*128
    float s[4] = {0.f, 0.f, 0.f, 0.f};
    for (int k = 0; k < ns; ++k) {
        ushort4 p = *reinterpret_cast<const ushort4*>(&P[(size_t)k * MN + i]);
        s[0] += bits2f(p.x); s[1] += bits2f(p.y); s[2] += bits2f(p.z); s[3] += bits2f(p.w);
    }
    float4 o = {s[0], s[1], s[2], s[3]};
    *reinterpret_cast<float4*>(&XDP[i]) = o;
    int col = (int)(i & (XDP_LD - 1));
    if (col < DTR) {
        size_t row = i >> 7;
        bf16 r[4];
#pragma unroll
        for (int j = 0; j < 4; ++j) r[j] = __float2bfloat16(s[j]);
        *reinterpret_cast<ushort4*>(&XDdt[row * DTR + col]) = *reinterpret_cast<ushort4*>(r);
    }
}

// ---------------- dt GEMM fallback (vector, K=64, reads XDP fp32) ----------------
__global__ __launch_bounds__(256) void gemm_dt(const float* __restrict__ A,   // lda=128
                                               const float* __restrict__ Bw,  // 64 x 2048 f32
                                               const float* __restrict__ bias,
                                               bf16* __restrict__ Cb, int M, int N) {
    __shared__ float As[16][68];
    __shared__ float Bs[16][68];
    int tid = threadIdx.x;
    int bm = blockIdx.y * 64, bn = blockIdx.x * 64;
    int tx = tid & 15, ty = tid >> 4;
    float acc[4][4];
#pragma unroll
    for (int i = 0; i < 4; ++i)
#pragma unroll
        for (int j = 0; j < 4; ++j) acc[i][j] = 0.f;
    int arow = tid >> 2, acg = (tid & 3) * 4;
    int brow = tid >> 4, bcol = (tid & 15) * 4;
    for (int k0 = 0; k0 < DTR; k0 += 16) {
        float4 av = *reinterpret_cast<const float4*>(&A[(size_t)(bm + arow) * XDP_LD + k0 + acg]);
        As[acg + 0][arow] = av.x; As[acg + 1][arow] = av.y;
        As[acg + 2][arow] = av.z; As[acg + 3][arow] = av.w;
        float4 bv = *reinterpret_cast<const float4*>(&Bw[(size_t)(k0 + brow) * N + bn + bcol]);
        Bs[brow][bcol + 0] = bv.x; Bs[brow][bcol + 1] = bv.y;
        Bs[brow][bcol + 2] = bv.z; Bs[brow][bcol + 3] = bv.w;
        __syncthreads();
#pragma unroll
        for (int kk = 0; kk < 16; ++kk) {
            float4 a = *reinterpret_cast<const float4*>(&As[kk][ty * 4]);
            float4 b = *reinterpret_cast<const float4*>(&Bs[kk][tx * 4]);
            acc[0][0] += a.x * b.x; acc[0][1] += a.x * b.y; acc[0][2] += a.x * b.z; acc[0][3] += a.x * b.w;
            acc[1][0] += a.y * b.x; acc[1][1] += a.y * b.y; acc[1][2] += a.y * b.z; acc[1][3] += a.y * b.w;
            acc[2][0] += a.z * b.x; acc[2][1] += a.z * b.y; acc[2][2] += a.z * b.z; acc[2][3] += a.z * b.w;
            acc[3][0] += a.w * b.x; acc[3][1] += a.w * b.y; acc[3][2] += a.w * b.z; acc[3][3] += a.w * b.w;
        }
        __syncthreads();
    }
    int row0 = bm + ty * 4, col0 = bn + tx * 4;
#pragma unroll
    for (int i = 0; i < 4; ++i)
#pragma unroll
        for (int j = 0; j < 4; ++j) {
            float v = acc[i][j] + bias[col0 + j];
            Cb[(size_t)(row0 + i) * N + col0 + j] = __float2bfloat16(softplus_fast(v));
        }
}

// ---------------- depthwise causal conv (fwd) + anti-causal (bwd) + SiLU ----------------
// Vectorized (G13): 1 thread = 8 consecutive channels; taps are bf16x8 16B loads,
// weights contiguous float4s, outputs bf16x8.
__global__ __launch_bounds__(256) void conv_kernel(const bf16* __restrict__ XZ,
                                                   const float* __restrict__ wf, const float* __restrict__ bf_,
                                                   const float* __restrict__ wb, const float* __restrict__ bb_,
                                                   bf16* __restrict__ XCF, bf16* __restrict__ XCB) {
    int idx = blockIdx.x * 256 + threadIdx.x;   // over T_TOK*DI/8
    int cg = idx & (DI / 8 - 1);
    int c0 = cg * 8;
    int g = idx >> 8;                 // token index
    int l = g & (SEQ - 1);
    int b = g >> 10;
    float sf[8], sb[8];
    float4 wfv[8], wbv[8];
#pragma unroll
    for (int u = 0; u < 8; ++u) {
        wfv[u] = *(const float4*)&wf[(c0 + u) * 4];
        wbv[u] = *(const float4*)&wb[(c0 + u) * 4];
        sf[u] = bf_[c0 + u];
        sb[u] = bb_[c0 + u];
    }
#pragma unroll
    for (int j = 0; j < 4; ++j) {
        int lf = l - 3 + j;
        if (lf >= 0) {
            bf16x8 v = *(const bf16x8*)&XZ[((size_t)(b * SEQ + lf)) * N2 + c0];
#pragma unroll
            for (int u = 0; u < 8; ++u) {
                float w = (j == 0) ? wfv[u].x : (j == 1) ? wfv[u].y : (j == 2) ? wfv[u].z : wfv[u].w;
                sf[u] += w * bits2f((unsigned short)v[u]);
            }
        }
        int lb = l + 3 - j;
        if (lb < SEQ) {
            bf16x8 v = *(const bf16x8*)&XZ[((size_t)(b * SEQ + lb)) * N2 + c0];
#pragma unroll
            for (int u = 0; u < 8; ++u) {
                float w = (j == 0) ? wbv[u].x : (j == 1) ? wbv[u].y : (j == 2) ? wbv[u].z : wbv[u].w;
                sb[u] += w * bits2f((unsigned short)v[u]);
            }
        }
    }
    bf16 rf[8], rb[8];
#pragma unroll
    for (int u = 0; u < 8; ++u) {
        rf[u] = __float2bfloat16(sf[u] / (1.f + __expf(-sf[u])));
        rb[u] = __float2bfloat16(sb[u] / (1.f + __expf(-sb[u])));
    }
    size_t o = (size_t)g * DI + c0;
    *(bf16x8*)&XCF[o] = *(bf16x8*)rf;
    *(bf16x8*)&XCB[o] = *(bf16x8*)rb;
}

// ---------------- chunked selective scan (3 kernels, HW stream barriers) ----------------
// NC=32 (CLEN=32). 2 threads per channel (8 states each); DT/XC tiles bulk-staged in LDS.
// Power-chain dA (R11, +10us): A_log = log(tile(arange(1..16))) gives A[c][n] = -(n+1),
// so exp(dt*A[n]) = r^(n+1), r = exp(dt*aunit). 1 exp + mults replaces 8 exps; runtime
// per-thread pattern check falls back to generic path.
template <int NC, bool FINAL>
__global__ __launch_bounds__(256) void scan_chunk(const bf16* __restrict__ DTF_, const bf16* __restrict__ DTB_,
                                                  const bf16* __restrict__ XCF_, const bf16* __restrict__ XCB_,
                                                  const float* __restrict__ XDP,
                                                  const float* __restrict__ Af, const float* __restrict__ Ab,
                                                  const float* __restrict__ Df, const float* __restrict__ Db,
                                                  float* __restrict__ HLOC, float* __restrict__ SUMDT,
                                                  bf16* __restrict__ YCAT) {
    constexpr int CL = SEQ / NC;
    __shared__ float bsl[CL][32];
    __shared__ bf16 dtl[CL][128];
    __shared__ bf16 xcl[CL][128];
    int tid = threadIdx.x;
    int sg = tid & 1;                          // state group: states sg*8 .. sg*8+7
    int cl = tid >> 1;                         // channel local 0..127
    int cbase = blockIdx.x * 128;
    int c = cbase + cl;
    int b = blockIdx.y;
    int dir = (int)blockIdx.z >= NC;
    int chunk = blockIdx.z - dir * NC;
    const bf16* DT = dir ? DTB_ : DTF_;
    const bf16* XC = dir ? XCB_ : XCF_;
    // stage B/C rows for the whole chunk: CL tokens x 32 floats
    for (int i = tid; i < CL * 8; i += 256) {
        int it = i >> 3, j4 = (i & 7) * 4;
        int sit = chunk * CL + it;
        int l = dir ? (SEQ - 1 - sit) : sit;
        size_t row = (size_t)dir * T_TOK + (size_t)b * SEQ + l;
        *(float4*)&bsl[it][j4] = *(const float4*)&XDP[row * XDP_LD + DTR + j4];
    }
    // stage DT/XC tiles: CL tokens x 128 channels, 16B chunks, fully coalesced
    for (int ch = tid; ch < CL * 16; ch += 256) {
        int it = ch >> 4, of = (ch & 15) * 8;
        int sit = chunk * CL + it;
        int l = dir ? (SEQ - 1 - sit) : sit;
        size_t g = (size_t)b * SEQ + l;
        *(bf16x8*)&dtl[it][of] = *(const bf16x8*)&DT[g * DI + cbase + of];
        *(bf16x8*)&xcl[it][of] = *(const bf16x8*)&XC[g * DI + cbase + of];
    }
    const float* Al = dir ? Ab : Af;
    int sg8 = sg * 8;
    float A[8];
#pragma unroll
    for (int n = 0; n < 8; ++n) A[n] = -__expf(Al[c * NST + sg8 + n]);
    // pattern check: A[n] == aunit * (sg8+1+n) with aunit = A[0]/(sg8+1)?
    float aunit = A[0] / (float)(sg8 + 1);
    bool fastp = true;
#pragma unroll
    for (int n = 1; n < 8; ++n) {
        float k = A[n] / aunit;
        fastp = fastp && (fabsf(k - (float)(sg8 + 1 + n)) < 1e-3f);
    }
    size_t base = ((((size_t)dir * BATCH + b) * NC + chunk) * DI + c);
    float h[8];
    float Dv = 0.f;
    if (FINAL) {
#pragma unroll
        for (int n = 0; n < 8; ++n) h[n] = HLOC[base * NST + sg8 + n];
        Dv = (dir ? Db : Df)[c];
    } else {
#pragma unroll
        for (int n = 0; n < 8; ++n) h[n] = 0.f;
    }
    __syncthreads();
    float sumdt = 0.f;
    for (int it = 0; it < CL; ++it) {
        int sit = chunk * CL + it;
        int l = dir ? (SEQ - 1 - sit) : sit;
        size_t g = (size_t)b * SEQ + l;
        float dt = b2f(dtl[it][cl]);
        float xc = b2f(xcl[it][cl]);
        float dtxc = dt * xc;
        const float* bs = &bsl[it][sg8];
        float da[8];
        if (fastp) {
            float r = __expf(dt * aunit);
            float p = r;
            if (sg) { float r2 = r * r; float r4 = r2 * r2; float r8 = r4 * r4; p = r8 * r; }
            da[0] = p;
#pragma unroll
            for (int n = 1; n < 8; ++n) { p *= r; da[n] = p; }
        } else {
#pragma unroll
            for (int n = 0; n < 8; ++n) da[n] = __expf(dt * A[n]);
        }
        if (FINAL) {
            float y = 0.f;
#pragma unroll
            for (int n = 0; n < 8; ++n) {
                h[n] = da[n] * h[n] + dtxc * bs[n];
                y += h[n] * bs[NST + n];
            }
            y += __shfl_xor(y, 1);
            if (!sg) YCAT[g * N2 + dir * DI + c] = __float2bfloat16(y + xc * Dv);
        } else {
            sumdt += dt;
#pragma unroll
            for (int n = 0; n < 8; ++n)
                h[n] = da[n] * h[n] + dtxc * bs[n];
        }
    }
    if (!FINAL) {
#pragma unroll
        for (int n = 0; n < 8; ++n) HLOC[base * NST + sg8 + n] = h[n];
        if (!sg) SUMDT[base] = sumdt;
    }
}

// phase B: sequential combine over chunks; rewrites HLOC[k] with carry-in h for chunk k
__global__ __launch_bounds__(256) void scan_combine(float* __restrict__ HLOC,
                                                    const float* __restrict__ SUMDT,
                                                    const float* __restrict__ Af,
                                                    const float* __restrict__ Ab, int nchunk) {
    int idx = blockIdx.x * 256 + threadIdx.x;   // over 2*BATCH*DI*NST = 131072
    int n = idx & 15;
    int c = (idx >> 4) & (DI - 1);
    int b = (idx >> 15) & 1;
    int dir = idx >> 16;
    float A = -__expf((dir ? Ab : Af)[c * NST + n]);
    float h = 0.f;
    for (int k = 0; k < nchunk; ++k) {
        size_t base = ((((size_t)dir * BATCH + b) * nchunk + k) * DI + c);
        float P = __expf(A * SUMDT[base]);
        float hl = HLOC[base * NST + n];
        HLOC[base * NST + n] = h;
        h = P * h + hl;
    }
}

// ---------------- gating fallback: YM *= silu(z) ----------------
__global__ __launch_bounds__(256) void gate_kernel(bf16* __restrict__ YM, const bf16* __restrict__ XZ) {
    int idx = blockIdx.x * 256 + threadIdx.x;  // over T_TOK*DI
    int t = idx >> 11;
    int c = idx & (DI - 1);
    float z = b2f(XZ[(size_t)t * N2 + DI + c]);
    float y = b2f(YM[idx]);
    YM[idx] = __float2bfloat16(y * (z / (1.f + __expf(-z))));
}

extern "C" void kernel_launch(void* const* d_in, const int* in_sizes, int n_in,
                              void* d_out, int out_size, void* d_ws, size_t ws_size,
                              hipStream_t stream) {
    const float* x       = (const float*)d_in[0];
    const float* gamma   = (const float*)d_in[1];
    const float* beta    = (const float*)d_in[2];
    const float* in_w    = (const float*)d_in[3];
    const float* conv_w  = (const float*)d_in[4];
    const float* conv_b  = (const float*)d_in[5];
    const float* xproj_w = (const float*)d_in[6];
    const float* dt_w    = (const float*)d_in[7];
    const float* dt_b    = (const float*)d_in[8];
    const float* A_log   = (const float*)d_in[9];
    const float* D_skip  = (const float*)d_in[10];
    const float* conv_w_b  = (const float*)d_in[11];
    const float* conv_b_b  = (const float*)d_in[12];
    const float* xproj_w_b = (const float*)d_in[13];
    const float* dt_w_b    = (const float*)d_in[14];
    const float* dt_b_b    = (const float*)d_in[15];
    const float* A_log_b   = (const float*)d_in[16];
    const float* D_skip_b  = (const float*)d_in[17];
    const float* merge_w   = (const float*)d_in[18];
    const float* out_w     = (const float*)d_in[19];
    float* out = (float*)d_out;

    // ---- base workspace layout ----
    char* w = (char*)d_ws;
    size_t off = 0;
    bf16* H       = (bf16*)(w + off); off += (size_t)T_TOK * DM * 2;          //  4.19 MB
    bf16* XZ      = (bf16*)(w + off); off += (size_t)T_TOK * N2 * 2;          // 16.78 MB
    bf16* XCF     = (bf16*)(w + off); off += (size_t)T_TOK * DI * 2;          //  8.39 MB
    bf16* XCB     = (bf16*)(w + off); off += (size_t)T_TOK * DI * 2;          //  8.39 MB
    bf16* XPF     = (bf16*)(w + off); off += (size_t)XDP_LD * DI * 2;         //  0.52 MB
    bf16* XPB     = (bf16*)(w + off); off += (size_t)XDP_LD * DI * 2;         //  0.52 MB
    float* XDP    = (float*)(w + off); off += (size_t)2 * T_TOK * XDP_LD * 4; //  2.10 MB
    bf16* DTF     = (bf16*)(w + off); off += (size_t)T_TOK * DI * 2;          //  8.39 MB
    bf16* DTB     = (bf16*)(w + off); off += (size_t)T_TOK * DI * 2;          //  8.39 MB (contig after DTF)
    bf16* YCAT    = (bf16*)(w + off); off += (size_t)T_TOK * N2 * 2;          // 16.78 MB
    bf16* in_wT   = (bf16*)(w + off); off += (size_t)N2 * DM * 2;             //  8.39 MB
    bf16* out_wT  = (bf16*)(w + off); off += (size_t)DM * DI * 2;             //  4.19 MB
    bf16* merge_wT= (bf16*)(w + off); off += (size_t)DI * N2 * 2;             // 16.78 MB
    bf16* dtwT    = (bf16*)(w + off); off += (size_t)2 * DI * DTR * 2;        //  0.52 MB
    bf16* XDdt    = (bf16*)(w + off); off += (size_t)2 * T_TOK * DTR * 2;     //  0.52 MB
    // PART region: time-shared {xz partials | xdbl partials | HLOC+SUMDT | merge partials | out partials}
    char* PART = w + off;
    size_t avail = (ws_size > off) ? ws_size - off : 0;

    float* HLOC  = (float*)PART;                                              // 8.39 MB (NCHUNK=32)
    float* SUMDT = (float*)(PART + (size_t)2 * BATCH * NCHUNK * DI * NST * 4);// +0.52 MB
    bf16* Pb     = (bf16*)PART;                                               // split-K bf16 partials
    bf16* YM     = DTF;    // alias: DTF dead after scan C

    size_t MNm = (size_t)T_TOK * DI;          // merge partial elems
    size_t MNo = (size_t)T_TOK * DM;          // out partial elems
    size_t MNx = (size_t)2 * T_TOK * XDP_LD;  // xdbl partial elems
    size_t MNz = (size_t)T_TOK * N2;          // xz partial elems
    int s_merge = (avail >= 4 * MNm * 2) ? 4 : (avail >= 2 * MNm * 2) ? 2 : 0;
    int s_out   = (avail >= 4 * MNo * 2) ? 4 : (avail >= 2 * MNo * 2) ? 2 : 0;
    int s_xdbl  = (avail >= 16 * MNx * 2) ? 16 : (avail >= 8 * MNx * 2) ? 8 : (avail >= 4 * MNx * 2) ? 4 : 0;
    int s_xz    = (avail >= 2 * MNz * 2) ? 2 : 0;

    // 1. mega prep: LN + in_wT + out_wT + merge_wT + xproj/dtw
    prep_mega<<<LN_BLKS + INW_T + OUTW_T + MRGW_T + SMALL_BLK, 256, 0, stream>>>(
        x, gamma, beta, H, in_w, in_wT, out_w, out_wT, merge_w, merge_wT,
        xproj_w, xproj_w_b, XPF, XPB, dt_w, dt_w_b, dtwT);
    // 2. xz = H @ in_w  (M=2048, N=4096, K=1024) -> XZ bf16
    if (s_xz) {
        gemm256<3><<<dim3(N2 / 128, T_TOK / 256, s_xz), 512, 0, stream>>>(
            H, in_wT, nullptr, Pb, T_TOK, N2, DM);
        reduce_plain<<<(int)(MNz / 4 / 256), 256, 0, stream>>>(Pb, s_xz, MNz, XZ);
    } else {
        mfma_gemm<0><<<dim3(N2 / 128, T_TOK / 128), 256, 0, stream>>>(
            H, in_wT, in_wT, 1 << 30, XZ, nullptr, nullptr, nullptr, nullptr, nullptr, T_TOK, N2, DM);
    }
    // 3. depthwise conv + silu, both dirs (vectorized: 8 channels/thread)
    conv_kernel<<<(T_TOK * DI / 8) / 256, 256, 0, stream>>>(XZ, conv_w, conv_b, conv_w_b, conv_b_b, XCF, XCB);
    // 4. x_dbl (padded): XDP = [XCF;XCB] @ xproj (M=4096, N=128, K=2048), B per dir
    if (s_xdbl) {
        mfma_gemm<3><<<dim3(1, (2 * T_TOK) / 128, s_xdbl), 256, 0, stream>>>(
            XCF, XPF, XPB, (T_TOK / 128), nullptr, nullptr, nullptr, Pb, nullptr, nullptr,
            2 * T_TOK, XDP_LD, DI);
        reduce_xdbl<<<(int)(MNx / 4 / 256), 256, 0, stream>>>(Pb, s_xdbl, MNx, XDP, XDdt);
        // 5. dt = softplus(XDdt @ dt_w + dt_b) via MFMA (M=4096 both dirs, N=2048, K=64)
        mfma_gemm<4><<<dim3(DI / 128, (2 * T_TOK) / 128), 256, 0, stream>>>(
            XDdt, dtwT, dtwT + (size_t)DI * DTR, (T_TOK / 128), DTF, nullptr, nullptr, nullptr,
            dt_b, dt_b_b, 2 * T_TOK, DI, DTR);
    } else {
        mfma_gemm<2><<<dim3(1, (2 * T_TOK) / 128), 256, 0, stream>>>(
            XCF, XPF, XPB, (T_TOK / 128), nullptr, nullptr, XDP, nullptr, nullptr, nullptr,
            2 * T_TOK, XDP_LD, DI);
        gemm_dt<<<dim3(DI / 64, T_TOK / 64), 256, 0, stream>>>(XDP, dt_w, dt_b, DTF, T_TOK, DI);
        gemm_dt<<<dim3(DI / 64, T_TOK / 64), 256, 0, stream>>>(XDP + (size_t)T_TOK * XDP_LD, dt_w_b, dt_b_b, DTB, T_TOK, DI);
    }
    // 6-8. chunked scan (3 kernels; stream boundaries are the grid barriers)
    scan_chunk<NCHUNK, false><<<dim3(DI / 128, BATCH, 2 * NCHUNK), 256, 0, stream>>>(
        DTF, DTB, XCF, XCB, XDP, A_log, A_log_b, D_skip, D_skip_b, HLOC, SUMDT, YCAT);
    scan_combine<<<(2 * BATCH * DI * NST) / 256, 256, 0, stream>>>(HLOC, SUMDT, A_log, A_log_b, NCHUNK);
    scan_chunk<NCHUNK, true><<<dim3(DI / 128, BATCH, 2 * NCHUNK), 256, 0, stream>>>(
        DTF, DTB, XCF, XCB, XDP, A_log, A_log_b, D_skip, D_skip_b, HLOC, SUMDT, YCAT);
    // 9. YM = silu(z) * (YCAT @ merge_w) (M=2048, N=2048, K=4096)
    if (s_merge) {
        gemm256<3><<<dim3(DI / 128, T_TOK / 256, s_merge), 512, 0, stream>>>(
            YCAT, merge_wT, nullptr, Pb, T_TOK, DI, N2);
        reduce_gate<<<(int)(MNm / 4 / 256), 256, 0, stream>>>(Pb, s_merge, MNm, XZ, YM);
    } else {
        mfma_gemm<0><<<dim3(DI / 128, T_TOK / 128), 256, 0, stream>>>(
            YCAT, merge_wT, merge_wT, 1 << 30, YM, nullptr, nullptr, nullptr, nullptr, nullptr,
            T_TOK, DI, N2);
        gate_kernel<<<(T_TOK * DI) / 256, 256, 0, stream>>>(YM, XZ);
    }
    // 10. out = x + YM @ out_w (M=2048, N=1024, K=2048), f32
    if (s_out) {
        mfma_gemm<3><<<dim3(DM / 128, T_TOK / 128, s_out), 256, 0, stream>>>(
            YM, out_wT, out_wT, 1 << 30, nullptr, nullptr, nullptr, Pb, nullptr, nullptr,
            T_TOK, DM, DI);
        reduce_out<<<(int)(MNo / 4 / 256), 256, 0, stream>>>(Pb, s_out, MNo, x, out);
    } else {
        mfma_gemm<1><<<dim3(DM / 128, T_TOK / 128), 256, 0, stream>>>(
            YM, out_wT, out_wT, 1 << 30, nullptr, x, out, nullptr, nullptr, nullptr,
            T_TOK, DM, DI);
    }
}